// Round 5
// baseline (898.272 us; speedup 1.0000x reference)
//
#include <hip/hip_runtime.h>
#include <math.h>

// Problem constants
#define NN      50000
#define EE      800000
#define DIN     256
#define HF      128
#define RR      8
#define NHEADS  8
#define DHH     16
#define OUTC    3
#define NB      ((NN + 255) / 256)   // 196 scan blocks

static inline int cdiv(long long a, int b) { return (int)((a + b - 1) / b); }

typedef __attribute__((ext_vector_type(8))) short short8;
typedef __attribute__((ext_vector_type(4))) float f32x4;

__device__ inline float bf2f(unsigned short u) {
    return __uint_as_float(((unsigned)u) << 16);
}
__device__ inline unsigned short f2bf(float f) {
    unsigned u = __float_as_uint(f);
    u += 0x7fffu + ((u >> 16) & 1u);   // RNE
    return (unsigned short)(u >> 16);
}

// ================= weight transpose + hi/lo split =================
// src fp32 [K][128] -> dsthi/dstlo [128][ldk] bf16 at col offset k0
__global__ __launch_bounds__(256) void trans_split_kernel(const float* __restrict__ src,
                                                          unsigned short* __restrict__ dsthi,
                                                          unsigned short* __restrict__ dstlo,
                                                          int K, int k0, int ldk) {
    int i = blockIdx.x * 256 + threadIdx.x;
    if (i >= K * 128) return;
    int k = i >> 7, n = i & 127;
    float f = src[(size_t)k * 128 + n];
    unsigned short hi = f2bf(f);
    unsigned short lo = f2bf(f - bf2f(hi));
    dsthi[(size_t)n * ldk + k0 + k] = hi;
    dstlo[(size_t)n * ldk + k0 + k] = lo;
}

// ================= CSR build =================
__global__ __launch_bounds__(256) void count_kernel(const int* __restrict__ tgt,
                                                    int* __restrict__ cnt) {
    int i = blockIdx.x * 256 + threadIdx.x;
    if (i < EE) atomicAdd(&cnt[tgt[i]], 1);
}

__global__ __launch_bounds__(256) void scan1_kernel(const int* __restrict__ cnt,
                                                    int* __restrict__ bsum) {
    __shared__ int s[256];
    int t = threadIdx.x;
    int i = blockIdx.x * 256 + t;
    s[t] = (i < NN) ? cnt[i] : 0;
    __syncthreads();
    for (int off = 128; off > 0; off >>= 1) {
        if (t < off) s[t] += s[t + off];
        __syncthreads();
    }
    if (t == 0) bsum[blockIdx.x] = s[0];
}

__global__ __launch_bounds__(256) void scan2_kernel(const int* __restrict__ bsum,
                                                    int* __restrict__ bbase,
                                                    int* __restrict__ rowptr) {
    __shared__ int s[256];
    int t = threadIdx.x;
    int v = (t < NB) ? bsum[t] : 0;
    s[t] = v;
    __syncthreads();
    for (int off = 1; off < 256; off <<= 1) {
        int u = (t >= off) ? s[t - off] : 0;
        __syncthreads();
        s[t] += u;
        __syncthreads();
    }
    if (t < NB) bbase[t] = s[t] - v;
    if (t == NB - 1) rowptr[NN] = s[t];
}

__global__ __launch_bounds__(256) void scan3_kernel(const int* __restrict__ cnt,
                                                    const int* __restrict__ bbase,
                                                    int* __restrict__ rowptr,
                                                    int* __restrict__ cursor) {
    __shared__ int s[256];
    int t = threadIdx.x;
    int i = blockIdx.x * 256 + t;
    int v = (i < NN) ? cnt[i] : 0;
    s[t] = v;
    __syncthreads();
    for (int off = 1; off < 256; off <<= 1) {
        int u = (t >= off) ? s[t - off] : 0;
        __syncthreads();
        s[t] += u;
        __syncthreads();
    }
    if (i < NN) {
        int e = bbase[blockIdx.x] + s[t] - v;
        rowptr[i] = e;
        cursor[i] = e;
    }
}

__global__ __launch_bounds__(256) void fill_kernel(const int* __restrict__ src,
                                                   const int* __restrict__ tgt,
                                                   const int* __restrict__ et,
                                                   int* __restrict__ cursor,
                                                   int* __restrict__ csr_src,
                                                   int* __restrict__ csr_rel) {
    int e = blockIdx.x * 256 + threadIdx.x;
    if (e >= EE) return;
    int t = tgt[e];
    int pos = atomicAdd(&cursor[t], 1);
    csr_src[pos] = src[e];
    csr_rel[pos] = et[e];
}

// ================= MFMA GEMM, effective-fp32 via hi/lo split =================
// C[M,128](fp32) (+)= A[M,K](fp32) @ (Bhi+Blo)[128,K]^T  (+bias)(relu)
// A is split to (hi,lo) bf16 during LDS staging; 3 MFMAs: Ah*Bl + Al*Bh + Ah*Bh.
#define BK 32
#define APAD 36   // 72B row stride = 18 banks: 16 fragment rows hit 16 distinct bank starts

template <bool ACC, bool BIAS, bool RELU>
__global__ __launch_bounds__(256) void gemm_mfma(const float* __restrict__ A, int lda,
                                                 const unsigned short* __restrict__ Bthi,
                                                 const unsigned short* __restrict__ Btlo, int ldk,
                                                 float* __restrict__ C,
                                                 const float* __restrict__ bias,
                                                 int M, int K) {
    __shared__ unsigned short Ah[128][APAD];
    __shared__ unsigned short Al[128][APAD];
    __shared__ unsigned short Bh[128][APAD];
    __shared__ unsigned short Bl[128][APAD];
    const int tid  = threadIdx.x;
    const int m0   = blockIdx.x * 128;
    const int w    = tid >> 6;
    const int lane = tid & 63;
    const int lrow = lane & 15;
    const int q    = lane >> 4;

    f32x4 acc[2][8];
#pragma unroll
    for (int t = 0; t < 2; t++)
#pragma unroll
        for (int c = 0; c < 8; c++) acc[t][c] = (f32x4){0.f, 0.f, 0.f, 0.f};

    const int srow  = tid >> 1;          // 0..127
    const int spart = (tid & 1) * 16;    // 0 or 16

    for (int k0 = 0; k0 < K; k0 += BK) {
        // --- stage A: 128 rows x 32 fp32 -> hi/lo bf16 planes ---
        {
            int gm = m0 + srow;
            float va[16];
            if (gm < M) {
                const float* ap = &A[(size_t)gm * lda + k0 + spart];
#pragma unroll
                for (int j = 0; j < 4; j++) {
                    float4 v = *reinterpret_cast<const float4*>(ap + j * 4);
                    va[j * 4 + 0] = v.x; va[j * 4 + 1] = v.y; va[j * 4 + 2] = v.z; va[j * 4 + 3] = v.w;
                }
            } else {
#pragma unroll
                for (int j = 0; j < 16; j++) va[j] = 0.f;
            }
            unsigned hw[8], lw[8];
#pragma unroll
            for (int j = 0; j < 8; j++) {
                unsigned short h0 = f2bf(va[2 * j]);
                unsigned short h1 = f2bf(va[2 * j + 1]);
                unsigned short l0 = f2bf(va[2 * j] - bf2f(h0));
                unsigned short l1 = f2bf(va[2 * j + 1] - bf2f(h1));
                hw[j] = (unsigned)h0 | ((unsigned)h1 << 16);
                lw[j] = (unsigned)l0 | ((unsigned)l1 << 16);
            }
            *reinterpret_cast<uint4*>(&Ah[srow][spart])     = make_uint4(hw[0], hw[1], hw[2], hw[3]);
            *reinterpret_cast<uint4*>(&Ah[srow][spart + 8]) = make_uint4(hw[4], hw[5], hw[6], hw[7]);
            *reinterpret_cast<uint4*>(&Al[srow][spart])     = make_uint4(lw[0], lw[1], lw[2], lw[3]);
            *reinterpret_cast<uint4*>(&Al[srow][spart + 8]) = make_uint4(lw[4], lw[5], lw[6], lw[7]);
        }
        // --- stage B hi/lo ---
        {
            const unsigned short* bh = &Bthi[(size_t)srow * ldk + k0 + spart];
            const unsigned short* bl = &Btlo[(size_t)srow * ldk + k0 + spart];
            *reinterpret_cast<uint4*>(&Bh[srow][spart])     = *reinterpret_cast<const uint4*>(bh);
            *reinterpret_cast<uint4*>(&Bh[srow][spart + 8]) = *reinterpret_cast<const uint4*>(bh + 8);
            *reinterpret_cast<uint4*>(&Bl[srow][spart])     = *reinterpret_cast<const uint4*>(bl);
            *reinterpret_cast<uint4*>(&Bl[srow][spart + 8]) = *reinterpret_cast<const uint4*>(bl + 8);
        }
        __syncthreads();

        short8 ah[2], al[2];
#pragma unroll
        for (int t = 0; t < 2; t++) {
            ah[t] = *reinterpret_cast<const short8*>(&Ah[w * 32 + t * 16 + lrow][q * 8]);
            al[t] = *reinterpret_cast<const short8*>(&Al[w * 32 + t * 16 + lrow][q * 8]);
        }
#pragma unroll
        for (int c = 0; c < 8; c++) {
            short8 bh = *reinterpret_cast<const short8*>(&Bh[c * 16 + lrow][q * 8]);
            short8 bl = *reinterpret_cast<const short8*>(&Bl[c * 16 + lrow][q * 8]);
#pragma unroll
            for (int t = 0; t < 2; t++) {
                acc[t][c] = __builtin_amdgcn_mfma_f32_16x16x32_bf16(ah[t], bl, acc[t][c], 0, 0, 0);
                acc[t][c] = __builtin_amdgcn_mfma_f32_16x16x32_bf16(al[t], bh, acc[t][c], 0, 0, 0);
                acc[t][c] = __builtin_amdgcn_mfma_f32_16x16x32_bf16(ah[t], bh, acc[t][c], 0, 0, 0);
            }
        }
        __syncthreads();
    }

#pragma unroll
    for (int t = 0; t < 2; t++) {
#pragma unroll
        for (int r = 0; r < 4; r++) {
            int gm = m0 + w * 32 + t * 16 + q * 4 + r;
            if (gm >= M) continue;
#pragma unroll
            for (int c = 0; c < 8; c++) {
                int gn = c * 16 + lrow;
                float v = acc[t][c][r];
                if (BIAS) v += bias[gn];
                if (ACC)  v += C[(size_t)gm * HF + gn];
                if (RELU) v = fmaxf(v, 0.f);
                C[(size_t)gm * HF + gn] = v;
            }
        }
    }
}

// ================= RGCN gather-aggregate pass (NR relations [+ self row]) =================
// agg[t, j, :] = mean_{e: tgt=t, rel=rbase+j} h[src_e, :]; if SELF, extra block = h[t,:]
template <int NR, bool SELF>
__global__ __launch_bounds__(256) void rgcn_agg_part(const float* __restrict__ h,
                                                     const int* __restrict__ rowptr,
                                                     const int* __restrict__ csr_src,
                                                     const int* __restrict__ csr_rel,
                                                     float* __restrict__ agg,
                                                     int rbase) {
    int w = (blockIdx.x * 256 + threadIdx.x) >> 6;
    if (w >= NN) return;
    int lane = threadIdx.x & 63;
    int c0 = lane * 2;
    int beg = rowptr[w], end = rowptr[w + 1];
    float ax[NR], ay[NR];
    int cnt[NR];
#pragma unroll
    for (int r = 0; r < NR; r++) { ax[r] = 0.f; ay[r] = 0.f; cnt[r] = 0; }
    for (int e = beg; e < end; e++) {
        int r = csr_rel[e] - rbase;
        if ((unsigned)r >= (unsigned)NR) continue;
        int s = csr_src[e];
        float2 v = *reinterpret_cast<const float2*>(&h[(size_t)s * HF + c0]);
#pragma unroll
        for (int rr = 0; rr < NR; rr++) {
            if (r == rr) { ax[rr] += v.x; ay[rr] += v.y; cnt[rr]++; }
        }
    }
    const int STRIDE = (NR + (SELF ? 1 : 0)) * HF;
    float* o = &agg[(size_t)w * STRIDE + c0];
#pragma unroll
    for (int r = 0; r < NR; r++) {
        float inv = 1.f / (float)(cnt[r] > 1 ? cnt[r] : 1);
        *reinterpret_cast<float2*>(o + r * HF) = make_float2(ax[r] * inv, ay[r] * inv);
    }
    if (SELF) {
        float2 self = *reinterpret_cast<const float2*>(&h[(size_t)w * HF + c0]);
        *reinterpret_cast<float2*>(o + NR * HF) = self;
    }
}

// ================= GAT attention scores (z fp32) =================
__global__ __launch_bounds__(256) void att_scores(const float* __restrict__ z,
                                                  const float* __restrict__ att,
                                                  float* __restrict__ a_src,
                                                  float* __restrict__ a_tgt) {
    int i = blockIdx.x * 256 + threadIdx.x;
    if (i >= NN * NHEADS) return;
    int n = i >> 3, hd = i & 7;
    const float* zp = &z[(size_t)n * HF + hd * DHH];
    const float* as = &att[hd * 2 * DHH];
    float s = 0.f, t = 0.f;
#pragma unroll
    for (int d = 0; d < DHH; d++) {
        float v = zp[d];
        s += v * as[d];
        t += v * as[DHH + d];
    }
    a_src[i] = s;
    a_tgt[i] = t;
}

// ================= GAT: wave/node online softmax + Wf GEMV + log_softmax =================
__global__ __launch_bounds__(256) void gat_kernel(const int* __restrict__ rowptr,
                                                  const int* __restrict__ csr_src,
                                                  const float* __restrict__ a_src,
                                                  const float* __restrict__ a_tgt,
                                                  const float* __restrict__ z,
                                                  const float* __restrict__ bg,
                                                  const float* __restrict__ Wf,
                                                  const float* __restrict__ bf,
                                                  float* __restrict__ out) {
    int w = (blockIdx.x * 256 + threadIdx.x) >> 6;
    if (w >= NN) return;
    int lane = threadIdx.x & 63;
    int hd = lane >> 3;
    int c0 = lane * 2;
    float at = a_tgt[w * NHEADS + hd];
    int beg = rowptr[w], end = rowptr[w + 1];

    float m = -1e30f, l = 0.f;
    float ax = 0.f, ay = 0.f;
    for (int e = beg; e < end; e++) {
        int s = csr_src[e];
        float a = a_src[s * NHEADS + hd] + at;
        a = a > 0.f ? a : 0.2f * a;
        float mn = fmaxf(m, a);
        float sc  = __expf(m - mn);
        float wgt = __expf(a - mn);
        l = l * sc + wgt;
        float2 zv = *reinterpret_cast<const float2*>(&z[(size_t)s * HF + c0]);
        ax = ax * sc + zv.x * wgt;
        ay = ay * sc + zv.y * wgt;
        m = mn;
    }
    float inv = 1.f / fmaxf(l, 1e-16f);
    float vx = ax * inv + bg[c0];
    float vy = ay * inv + bg[c0 + 1];

    float p0 = vx * Wf[c0 * 3 + 0] + vy * Wf[(c0 + 1) * 3 + 0];
    float p1 = vx * Wf[c0 * 3 + 1] + vy * Wf[(c0 + 1) * 3 + 1];
    float p2 = vx * Wf[c0 * 3 + 2] + vy * Wf[(c0 + 1) * 3 + 2];
#pragma unroll
    for (int off = 32; off > 0; off >>= 1) {
        p0 += __shfl_xor(p0, off);
        p1 += __shfl_xor(p1, off);
        p2 += __shfl_xor(p2, off);
    }
    if (lane == 0) {
        float l0 = p0 + bf[0], l1 = p1 + bf[1], l2 = p2 + bf[2];
        float mm = fmaxf(l0, fmaxf(l1, l2));
        float lse = mm + logf(expf(l0 - mm) + expf(l1 - mm) + expf(l2 - mm));
        out[(size_t)w * 3 + 0] = l0 - lse;
        out[(size_t)w * 3 + 1] = l1 - lse;
        out[(size_t)w * 3 + 2] = l2 - lse;
    }
}

// ================= launch =================
extern "C" void kernel_launch(void* const* d_in, const int* in_sizes, int n_in,
                              void* d_out, int out_size, void* d_ws, size_t ws_size,
                              hipStream_t stream) {
    const float* x     = (const float*)d_in[0];
    const int*   ei    = (const int*)d_in[1];
    const int*   etype = (const int*)d_in[2];
    const float* Wp    = (const float*)d_in[3];
    const float* bp    = (const float*)d_in[4];
    const float* W1    = (const float*)d_in[5];
    const float* root1 = (const float*)d_in[6];
    const float* b1    = (const float*)d_in[7];
    const float* W2    = (const float*)d_in[8];
    const float* root2 = (const float*)d_in[9];
    const float* b2    = (const float*)d_in[10];
    const float* Wg    = (const float*)d_in[11];
    const float* att   = (const float*)d_in[12];
    const float* bg    = (const float*)d_in[13];
    const float* Wf    = (const float*)d_in[14];
    const float* bf    = (const float*)d_in[15];
    (void)in_sizes; (void)n_in; (void)out_size; (void)ws_size;

    const int* srcv = ei;
    const int* tgtv = ei + EE;

    const int LDK9 = (RR + 1) * HF;  // 1152

    // ---- workspace layout (bytes), ~187.3 MB ----
    char* base = (char*)d_ws;
    float* agg   = (float*)(base + 0);            // N*640*4 = 128,000,000 (max pass)
    // GAT-phase aliases into agg region (agg dead then):
    float* zbuf  = (float*)(base + 0);            // 25,600,000
    float* a_src = (float*)(base + 26000000);     // 1,600,000
    float* a_tgt = (float*)(base + 28000000);     // 1,600,000
    float* h1    = (float*)(base + 128000000);    // 25,600,000
    float* h2    = (float*)(base + 153600000);    // 25,600,000
    int* csr_src = (int*)(base + 179200000);      // 3,200,000
    int* csr_rel = (int*)(base + 182400000);      // 3,200,000
    int* rowptr  = (int*)(base + 185600000);      // 200,016
    int* cursor  = (int*)(base + 185800016);      // 200,000
    int* cnt     = (int*)(base + 186000016);      // 200,000
    int* bsum    = (int*)(base + 186200016);      // 1,024
    int* bbase   = (int*)(base + 186201040);      // 1,024
    unsigned short* Wtp_hi = (unsigned short*)(base + 186202064); // 65,536
    unsigned short* Wtp_lo = (unsigned short*)(base + 186267600); // 65,536
    unsigned short* Wt1_hi = (unsigned short*)(base + 186333136); // 294,912
    unsigned short* Wt1_lo = (unsigned short*)(base + 186628048); // 294,912
    unsigned short* Wt2_hi = (unsigned short*)(base + 186922960); // 294,912
    unsigned short* Wt2_lo = (unsigned short*)(base + 187217872); // 294,912
    unsigned short* Wtg_hi = (unsigned short*)(base + 187512784); // 32,768
    unsigned short* Wtg_lo = (unsigned short*)(base + 187545552); // 32,768

    // ---- weight prep ----
    trans_split_kernel<<<cdiv(256 * 128, 256), 256, 0, stream>>>(Wp, Wtp_hi, Wtp_lo, 256, 0, 256);
    trans_split_kernel<<<cdiv(1024 * 128, 256), 256, 0, stream>>>(W1, Wt1_hi, Wt1_lo, 1024, 0, LDK9);
    trans_split_kernel<<<cdiv(128 * 128, 256), 256, 0, stream>>>(root1, Wt1_hi, Wt1_lo, 128, 1024, LDK9);
    trans_split_kernel<<<cdiv(1024 * 128, 256), 256, 0, stream>>>(W2, Wt2_hi, Wt2_lo, 1024, 0, LDK9);
    trans_split_kernel<<<cdiv(128 * 128, 256), 256, 0, stream>>>(root2, Wt2_hi, Wt2_lo, 128, 1024, LDK9);
    trans_split_kernel<<<cdiv(128 * 128, 256), 256, 0, stream>>>(Wg, Wtg_hi, Wtg_lo, 128, 0, 128);

    // ---- CSR build (multi-block scan) ----
    hipMemsetAsync(cnt, 0, (size_t)NN * 4, stream);
    count_kernel<<<cdiv(EE, 256), 256, 0, stream>>>(tgtv, cnt);
    scan1_kernel<<<NB, 256, 0, stream>>>(cnt, bsum);
    scan2_kernel<<<1, 256, 0, stream>>>(bsum, bbase, rowptr);
    scan3_kernel<<<NB, 256, 0, stream>>>(cnt, bbase, rowptr, cursor);
    fill_kernel<<<cdiv(EE, 256), 256, 0, stream>>>(srcv, tgtv, etype, cursor, csr_src, csr_rel);

    const int ggrid  = cdiv(NN, 128);   // 391
    const int nwgrid = cdiv(NN, 4);

    // ---- projection: h1 = x @ Wp + bp ----
    gemm_mfma<false, true, false><<<ggrid, 256, 0, stream>>>(x, DIN, Wtp_hi, Wtp_lo, DIN, h1, bp, NN, DIN);

    // ---- RGCN layer 1: h1 -> h2 (two passes, exact fp32 ACC) ----
    rgcn_agg_part<4, false><<<nwgrid, 256, 0, stream>>>(h1, rowptr, csr_src, csr_rel, agg, 0);
    gemm_mfma<false, false, false><<<ggrid, 256, 0, stream>>>(agg, 512, Wt1_hi, Wt1_lo, LDK9, h2, nullptr, NN, 512);
    rgcn_agg_part<4, true><<<nwgrid, 256, 0, stream>>>(h1, rowptr, csr_src, csr_rel, agg, 4);
    gemm_mfma<true, true, true><<<ggrid, 256, 0, stream>>>(agg, 640, Wt1_hi + 512, Wt1_lo + 512, LDK9, h2, b1, NN, 640);

    // ---- RGCN layer 2: h2 -> h1 ----
    rgcn_agg_part<4, false><<<nwgrid, 256, 0, stream>>>(h2, rowptr, csr_src, csr_rel, agg, 0);
    gemm_mfma<false, false, false><<<ggrid, 256, 0, stream>>>(agg, 512, Wt2_hi, Wt2_lo, LDK9, h1, nullptr, NN, 512);
    rgcn_agg_part<4, true><<<nwgrid, 256, 0, stream>>>(h2, rowptr, csr_src, csr_rel, agg, 4);
    gemm_mfma<true, true, true><<<ggrid, 256, 0, stream>>>(agg, 640, Wt2_hi + 512, Wt2_lo + 512, LDK9, h1, b2, NN, 640);

    // ---- GAT: z = h1 @ Wg ----
    gemm_mfma<false, false, false><<<ggrid, 256, 0, stream>>>(h1, HF, Wtg_hi, Wtg_lo, HF, zbuf, nullptr, NN, HF);
    att_scores<<<cdiv((long long)NN * NHEADS, 256), 256, 0, stream>>>(zbuf, att, a_src, a_tgt);
    gat_kernel<<<nwgrid, 256, 0, stream>>>(rowptr, csr_src, a_src, a_tgt, zbuf, bg, Wf, bf, (float*)d_out);
}

// Round 6
// 711.765 us; speedup vs baseline: 1.2620x; 1.2620x over previous
//
#include <hip/hip_runtime.h>
#include <math.h>

// Problem constants
#define NN      50000
#define EE      800000
#define DIN     256
#define HF      128
#define RR      8
#define NHEADS  8
#define DHH     16
#define OUTC    3
#define NB      ((NN + 255) / 256)   // 196 scan blocks

static inline int cdiv(long long a, int b) { return (int)((a + b - 1) / b); }

typedef __attribute__((ext_vector_type(8))) short short8;
typedef __attribute__((ext_vector_type(4))) float f32x4;

__device__ inline float bf2f(unsigned short u) {
    return __uint_as_float(((unsigned)u) << 16);
}
__device__ inline unsigned short f2bf(float f) {
    unsigned u = __float_as_uint(f);
    u += 0x7fffu + ((u >> 16) & 1u);   // RNE
    return (unsigned short)(u >> 16);
}

// ================= weight transpose + hi/lo split =================
// src fp32 [K][128] -> dsthi/dstlo [128][ldk] bf16 at col offset k0
__global__ __launch_bounds__(256) void trans_split_kernel(const float* __restrict__ src,
                                                          unsigned short* __restrict__ dsthi,
                                                          unsigned short* __restrict__ dstlo,
                                                          int K, int k0, int ldk) {
    int i = blockIdx.x * 256 + threadIdx.x;
    if (i >= K * 128) return;
    int k = i >> 7, n = i & 127;
    float f = src[(size_t)k * 128 + n];
    unsigned short hi = f2bf(f);
    unsigned short lo = f2bf(f - bf2f(hi));
    dsthi[(size_t)n * ldk + k0 + k] = hi;
    dstlo[(size_t)n * ldk + k0 + k] = lo;
}

// ================= CSR build =================
__global__ __launch_bounds__(256) void count_kernel(const int* __restrict__ tgt,
                                                    int* __restrict__ cnt) {
    int i = blockIdx.x * 256 + threadIdx.x;
    if (i < EE) atomicAdd(&cnt[tgt[i]], 1);
}

__global__ __launch_bounds__(256) void scan1_kernel(const int* __restrict__ cnt,
                                                    int* __restrict__ bsum) {
    __shared__ int s[256];
    int t = threadIdx.x;
    int i = blockIdx.x * 256 + t;
    s[t] = (i < NN) ? cnt[i] : 0;
    __syncthreads();
    for (int off = 128; off > 0; off >>= 1) {
        if (t < off) s[t] += s[t + off];
        __syncthreads();
    }
    if (t == 0) bsum[blockIdx.x] = s[0];
}

__global__ __launch_bounds__(256) void scan2_kernel(const int* __restrict__ bsum,
                                                    int* __restrict__ bbase,
                                                    int* __restrict__ rowptr) {
    __shared__ int s[256];
    int t = threadIdx.x;
    int v = (t < NB) ? bsum[t] : 0;
    s[t] = v;
    __syncthreads();
    for (int off = 1; off < 256; off <<= 1) {
        int u = (t >= off) ? s[t - off] : 0;
        __syncthreads();
        s[t] += u;
        __syncthreads();
    }
    if (t < NB) bbase[t] = s[t] - v;
    if (t == NB - 1) rowptr[NN] = s[t];
}

__global__ __launch_bounds__(256) void scan3_kernel(const int* __restrict__ cnt,
                                                    const int* __restrict__ bbase,
                                                    int* __restrict__ rowptr,
                                                    int* __restrict__ cursor) {
    __shared__ int s[256];
    int t = threadIdx.x;
    int i = blockIdx.x * 256 + t;
    int v = (i < NN) ? cnt[i] : 0;
    s[t] = v;
    __syncthreads();
    for (int off = 1; off < 256; off <<= 1) {
        int u = (t >= off) ? s[t - off] : 0;
        __syncthreads();
        s[t] += u;
        __syncthreads();
    }
    if (i < NN) {
        int e = bbase[blockIdx.x] + s[t] - v;
        rowptr[i] = e;
        cursor[i] = e;
    }
}

__global__ __launch_bounds__(256) void fill_kernel(const int* __restrict__ src,
                                                   const int* __restrict__ tgt,
                                                   const int* __restrict__ et,
                                                   int* __restrict__ cursor,
                                                   int* __restrict__ csr_src,
                                                   int* __restrict__ csr_rel) {
    int e = blockIdx.x * 256 + threadIdx.x;
    if (e >= EE) return;
    int t = tgt[e];
    int pos = atomicAdd(&cursor[t], 1);
    csr_src[pos] = src[e];
    csr_rel[pos] = et[e];
}

// ================= MFMA GEMM =================
// SPLITA=true : A fp32, split to hi/lo in LDS, 3 MFMAs (effective fp32)
// SPLITA=false: A bf16 single plane, 2 MFMAs (A-rounded, B exact)
// C fp32 [M,128]; optional bf16 mirror Cb.
#define BK 32
#define APAD 36   // 72B row stride

template <bool SPLITA, bool ACC, bool BIAS, bool RELU, bool BF16OUT>
__global__ __launch_bounds__(256) void gemm_mfma(const void* __restrict__ Av, int lda,
                                                 const unsigned short* __restrict__ Bthi,
                                                 const unsigned short* __restrict__ Btlo, int ldk,
                                                 float* __restrict__ C,
                                                 unsigned short* __restrict__ Cb,
                                                 const float* __restrict__ bias,
                                                 int M, int K) {
    __shared__ unsigned short Ah[128 * APAD];
    __shared__ unsigned short Al[(SPLITA ? 128 : 1) * APAD];
    __shared__ unsigned short Bh[128 * APAD];
    __shared__ unsigned short Bl[128 * APAD];
    const int tid  = threadIdx.x;
    const int m0   = blockIdx.x * 128;
    const int w    = tid >> 6;
    const int lane = tid & 63;
    const int lrow = lane & 15;
    const int q    = lane >> 4;

    f32x4 acc[2][8];
#pragma unroll
    for (int t = 0; t < 2; t++)
#pragma unroll
        for (int c = 0; c < 8; c++) acc[t][c] = (f32x4){0.f, 0.f, 0.f, 0.f};

    const int srow  = tid >> 1;          // 0..127
    const int spart = (tid & 1) * 16;    // 0 or 16

    for (int k0 = 0; k0 < K; k0 += BK) {
        if (SPLITA) {
            const float* A = (const float*)Av;
            int gm = m0 + srow;
            float va[16];
            if (gm < M) {
                const float* ap = &A[(size_t)gm * lda + k0 + spart];
#pragma unroll
                for (int j = 0; j < 4; j++) {
                    float4 v = *reinterpret_cast<const float4*>(ap + j * 4);
                    va[j * 4 + 0] = v.x; va[j * 4 + 1] = v.y; va[j * 4 + 2] = v.z; va[j * 4 + 3] = v.w;
                }
            } else {
#pragma unroll
                for (int j = 0; j < 16; j++) va[j] = 0.f;
            }
            unsigned hw[8], lw[8];
#pragma unroll
            for (int j = 0; j < 8; j++) {
                unsigned short h0 = f2bf(va[2 * j]);
                unsigned short h1 = f2bf(va[2 * j + 1]);
                unsigned short l0 = f2bf(va[2 * j] - bf2f(h0));
                unsigned short l1 = f2bf(va[2 * j + 1] - bf2f(h1));
                hw[j] = (unsigned)h0 | ((unsigned)h1 << 16);
                lw[j] = (unsigned)l0 | ((unsigned)l1 << 16);
            }
            *reinterpret_cast<uint4*>(&Ah[srow * APAD + spart])     = make_uint4(hw[0], hw[1], hw[2], hw[3]);
            *reinterpret_cast<uint4*>(&Ah[srow * APAD + spart + 8]) = make_uint4(hw[4], hw[5], hw[6], hw[7]);
            *reinterpret_cast<uint4*>(&Al[srow * APAD + spart])     = make_uint4(lw[0], lw[1], lw[2], lw[3]);
            *reinterpret_cast<uint4*>(&Al[srow * APAD + spart + 8]) = make_uint4(lw[4], lw[5], lw[6], lw[7]);
        } else {
            const unsigned short* A = (const unsigned short*)Av;
            int gm = m0 + srow;
            uint4 v  = make_uint4(0u, 0u, 0u, 0u);
            uint4 v2 = make_uint4(0u, 0u, 0u, 0u);
            if (gm < M) {
                const unsigned short* ap = &A[(size_t)gm * lda + k0 + spart];
                v  = *reinterpret_cast<const uint4*>(ap);
                v2 = *reinterpret_cast<const uint4*>(ap + 8);
            }
            *reinterpret_cast<uint4*>(&Ah[srow * APAD + spart])     = v;
            *reinterpret_cast<uint4*>(&Ah[srow * APAD + spart + 8]) = v2;
        }
        {
            const unsigned short* bh = &Bthi[(size_t)srow * ldk + k0 + spart];
            const unsigned short* bl = &Btlo[(size_t)srow * ldk + k0 + spart];
            *reinterpret_cast<uint4*>(&Bh[srow * APAD + spart])     = *reinterpret_cast<const uint4*>(bh);
            *reinterpret_cast<uint4*>(&Bh[srow * APAD + spart + 8]) = *reinterpret_cast<const uint4*>(bh + 8);
            *reinterpret_cast<uint4*>(&Bl[srow * APAD + spart])     = *reinterpret_cast<const uint4*>(bl);
            *reinterpret_cast<uint4*>(&Bl[srow * APAD + spart + 8]) = *reinterpret_cast<const uint4*>(bl + 8);
        }
        __syncthreads();

        short8 ah[2], al[2];
#pragma unroll
        for (int t = 0; t < 2; t++) {
            ah[t] = *reinterpret_cast<const short8*>(&Ah[(w * 32 + t * 16 + lrow) * APAD + q * 8]);
            if (SPLITA)
                al[t] = *reinterpret_cast<const short8*>(&Al[(w * 32 + t * 16 + lrow) * APAD + q * 8]);
        }
#pragma unroll
        for (int c = 0; c < 8; c++) {
            short8 bh = *reinterpret_cast<const short8*>(&Bh[(c * 16 + lrow) * APAD + q * 8]);
            short8 bl = *reinterpret_cast<const short8*>(&Bl[(c * 16 + lrow) * APAD + q * 8]);
#pragma unroll
            for (int t = 0; t < 2; t++) {
                acc[t][c] = __builtin_amdgcn_mfma_f32_16x16x32_bf16(ah[t], bl, acc[t][c], 0, 0, 0);
                if (SPLITA)
                    acc[t][c] = __builtin_amdgcn_mfma_f32_16x16x32_bf16(al[t], bh, acc[t][c], 0, 0, 0);
                acc[t][c] = __builtin_amdgcn_mfma_f32_16x16x32_bf16(ah[t], bh, acc[t][c], 0, 0, 0);
            }
        }
        __syncthreads();
    }

#pragma unroll
    for (int t = 0; t < 2; t++) {
#pragma unroll
        for (int r = 0; r < 4; r++) {
            int gm = m0 + w * 32 + t * 16 + q * 4 + r;
            if (gm >= M) continue;
#pragma unroll
            for (int c = 0; c < 8; c++) {
                int gn = c * 16 + lrow;
                float v = acc[t][c][r];
                if (BIAS) v += bias[gn];
                if (ACC)  v += C[(size_t)gm * HF + gn];
                if (RELU) v = fmaxf(v, 0.f);
                C[(size_t)gm * HF + gn] = v;
                if (BF16OUT) Cb[(size_t)gm * HF + gn] = f2bf(v);
            }
        }
    }
}

// ================= RGCN gather-aggregate: all 8 relations, one walk, bf16 in/out =================
// agg[t, r, :] = mean_{e: tgt=t, rel=r} hb[src_e, :]
__global__ __launch_bounds__(256) void rgcn_agg_all8(const unsigned short* __restrict__ hb,
                                                     const int* __restrict__ rowptr,
                                                     const int* __restrict__ csr_src,
                                                     const int* __restrict__ csr_rel,
                                                     unsigned short* __restrict__ agg) {
    int w = (blockIdx.x * 256 + threadIdx.x) >> 6;
    if (w >= NN) return;
    int lane = threadIdx.x & 63;
    int c0 = lane * 2;
    int beg = rowptr[w], end = rowptr[w + 1];
    float ax[RR], ay[RR];
    int cnt[RR];
#pragma unroll
    for (int r = 0; r < RR; r++) { ax[r] = 0.f; ay[r] = 0.f; cnt[r] = 0; }
    for (int e = beg; e < end; e++) {
        int r = csr_rel[e];
        int s = csr_src[e];
        unsigned hv = *reinterpret_cast<const unsigned*>(&hb[(size_t)s * HF + c0]);
        float f0 = bf2f((unsigned short)(hv & 0xffffu));
        float f1 = bf2f((unsigned short)(hv >> 16));
#pragma unroll
        for (int rr = 0; rr < RR; rr++) {
            if (r == rr) { ax[rr] += f0; ay[rr] += f1; cnt[rr]++; }
        }
    }
    unsigned short* o = &agg[(size_t)w * (RR * HF)];
#pragma unroll
    for (int r = 0; r < RR; r++) {
        float inv = 1.f / (float)(cnt[r] > 1 ? cnt[r] : 1);
        unsigned packed = (unsigned)f2bf(ax[r] * inv) | ((unsigned)f2bf(ay[r] * inv) << 16);
        *reinterpret_cast<unsigned*>(&o[r * HF + c0]) = packed;
    }
}

// ================= GAT attention scores (z fp32) =================
__global__ __launch_bounds__(256) void att_scores(const float* __restrict__ z,
                                                  const float* __restrict__ att,
                                                  float* __restrict__ a_src,
                                                  float* __restrict__ a_tgt) {
    int i = blockIdx.x * 256 + threadIdx.x;
    if (i >= NN * NHEADS) return;
    int n = i >> 3, hd = i & 7;
    const float* zp = &z[(size_t)n * HF + hd * DHH];
    const float* as = &att[hd * 2 * DHH];
    float s = 0.f, t = 0.f;
#pragma unroll
    for (int d = 0; d < DHH; d++) {
        float v = zp[d];
        s += v * as[d];
        t += v * as[DHH + d];
    }
    a_src[i] = s;
    a_tgt[i] = t;
}

// ================= GAT: wave/node online softmax (zb bf16 gather) + Wf GEMV + log_softmax =================
__global__ __launch_bounds__(256) void gat_kernel(const int* __restrict__ rowptr,
                                                  const int* __restrict__ csr_src,
                                                  const float* __restrict__ a_src,
                                                  const float* __restrict__ a_tgt,
                                                  const unsigned short* __restrict__ zb,
                                                  const float* __restrict__ bg,
                                                  const float* __restrict__ Wf,
                                                  const float* __restrict__ bf,
                                                  float* __restrict__ out) {
    int w = (blockIdx.x * 256 + threadIdx.x) >> 6;
    if (w >= NN) return;
    int lane = threadIdx.x & 63;
    int hd = lane >> 3;
    int c0 = lane * 2;
    float at = a_tgt[w * NHEADS + hd];
    int beg = rowptr[w], end = rowptr[w + 1];

    float m = -1e30f, l = 0.f;
    float ax = 0.f, ay = 0.f;
    for (int e = beg; e < end; e++) {
        int s = csr_src[e];
        float a = a_src[s * NHEADS + hd] + at;
        a = a > 0.f ? a : 0.2f * a;
        float mn = fmaxf(m, a);
        float sc  = __expf(m - mn);
        float wgt = __expf(a - mn);
        l = l * sc + wgt;
        unsigned zv = *reinterpret_cast<const unsigned*>(&zb[(size_t)s * HF + c0]);
        ax = ax * sc + bf2f((unsigned short)(zv & 0xffffu)) * wgt;
        ay = ay * sc + bf2f((unsigned short)(zv >> 16)) * wgt;
        m = mn;
    }
    float inv = 1.f / fmaxf(l, 1e-16f);
    float vx = ax * inv + bg[c0];
    float vy = ay * inv + bg[c0 + 1];

    float p0 = vx * Wf[c0 * 3 + 0] + vy * Wf[(c0 + 1) * 3 + 0];
    float p1 = vx * Wf[c0 * 3 + 1] + vy * Wf[(c0 + 1) * 3 + 1];
    float p2 = vx * Wf[c0 * 3 + 2] + vy * Wf[(c0 + 1) * 3 + 2];
#pragma unroll
    for (int off = 32; off > 0; off >>= 1) {
        p0 += __shfl_xor(p0, off);
        p1 += __shfl_xor(p1, off);
        p2 += __shfl_xor(p2, off);
    }
    if (lane == 0) {
        float l0 = p0 + bf[0], l1 = p1 + bf[1], l2 = p2 + bf[2];
        float mm = fmaxf(l0, fmaxf(l1, l2));
        float lse = mm + logf(expf(l0 - mm) + expf(l1 - mm) + expf(l2 - mm));
        out[(size_t)w * 3 + 0] = l0 - lse;
        out[(size_t)w * 3 + 1] = l1 - lse;
        out[(size_t)w * 3 + 2] = l2 - lse;
    }
}

// ================= launch =================
extern "C" void kernel_launch(void* const* d_in, const int* in_sizes, int n_in,
                              void* d_out, int out_size, void* d_ws, size_t ws_size,
                              hipStream_t stream) {
    const float* x     = (const float*)d_in[0];
    const int*   ei    = (const int*)d_in[1];
    const int*   etype = (const int*)d_in[2];
    const float* Wp    = (const float*)d_in[3];
    const float* bp    = (const float*)d_in[4];
    const float* W1    = (const float*)d_in[5];
    const float* root1 = (const float*)d_in[6];
    const float* b1    = (const float*)d_in[7];
    const float* W2    = (const float*)d_in[8];
    const float* root2 = (const float*)d_in[9];
    const float* b2    = (const float*)d_in[10];
    const float* Wg    = (const float*)d_in[11];
    const float* att   = (const float*)d_in[12];
    const float* bg    = (const float*)d_in[13];
    const float* Wf    = (const float*)d_in[14];
    const float* bf    = (const float*)d_in[15];
    (void)in_sizes; (void)n_in; (void)out_size; (void)ws_size;

    const int* srcv = ei;
    const int* tgtv = ei + EE;

    const int LDK9 = (RR + 1) * HF;  // 1152: cols 0-1023 = W_r, 1024-1151 = root

    // ---- workspace layout (bytes), ~187.6 MB ----
    char* base = (char*)d_ws;
    unsigned short* aggb = (unsigned short*)(base + 0);   // N*1024*2 = 102,400,000
    // GAT-phase aliases (aggb dead by then):
    float* z     = (float*)(base + 0);                    // 25,600,000
    unsigned short* zb = (unsigned short*)(base + 25600000); // 12,800,000
    float* a_src = (float*)(base + 38400000);             // 1,600,000
    float* a_tgt = (float*)(base + 40000000);             // 1,600,000
    float* h1    = (float*)(base + 102400000);            // 25,600,000
    float* h2    = (float*)(base + 128000000);            // 25,600,000
    unsigned short* h1b = (unsigned short*)(base + 153600000); // 12,800,000
    unsigned short* h2b = (unsigned short*)(base + 166400000); // 12,800,000
    int* csr_src = (int*)(base + 179200000);              // 3,200,000
    int* csr_rel = (int*)(base + 182400000);              // 3,200,000
    int* rowptr  = (int*)(base + 185600000);              // 200,016
    int* cursor  = (int*)(base + 185800016);              // 200,000
    int* cnt     = (int*)(base + 186000016);              // 200,000
    int* bsum    = (int*)(base + 186200016);              // 1,024
    int* bbase   = (int*)(base + 186201040);              // 1,024
    unsigned short* Wtp_hi = (unsigned short*)(base + 186202064); // 65,536
    unsigned short* Wtp_lo = (unsigned short*)(base + 186267600); // 65,536
    unsigned short* Wt1_hi = (unsigned short*)(base + 186333136); // 294,912
    unsigned short* Wt1_lo = (unsigned short*)(base + 186628048); // 294,912
    unsigned short* Wt2_hi = (unsigned short*)(base + 186922960); // 294,912
    unsigned short* Wt2_lo = (unsigned short*)(base + 187217872); // 294,912
    unsigned short* Wtg_hi = (unsigned short*)(base + 187512784); // 32,768
    unsigned short* Wtg_lo = (unsigned short*)(base + 187545552); // 32,768

    // ---- weight prep ----
    trans_split_kernel<<<cdiv(256 * 128, 256), 256, 0, stream>>>(Wp, Wtp_hi, Wtp_lo, 256, 0, 256);
    trans_split_kernel<<<cdiv(1024 * 128, 256), 256, 0, stream>>>(W1, Wt1_hi, Wt1_lo, 1024, 0, LDK9);
    trans_split_kernel<<<cdiv(128 * 128, 256), 256, 0, stream>>>(root1, Wt1_hi, Wt1_lo, 128, 1024, LDK9);
    trans_split_kernel<<<cdiv(1024 * 128, 256), 256, 0, stream>>>(W2, Wt2_hi, Wt2_lo, 1024, 0, LDK9);
    trans_split_kernel<<<cdiv(128 * 128, 256), 256, 0, stream>>>(root2, Wt2_hi, Wt2_lo, 128, 1024, LDK9);
    trans_split_kernel<<<cdiv(128 * 128, 256), 256, 0, stream>>>(Wg, Wtg_hi, Wtg_lo, 128, 0, 128);

    // ---- CSR build ----
    hipMemsetAsync(cnt, 0, (size_t)NN * 4, stream);
    count_kernel<<<cdiv(EE, 256), 256, 0, stream>>>(tgtv, cnt);
    scan1_kernel<<<NB, 256, 0, stream>>>(cnt, bsum);
    scan2_kernel<<<1, 256, 0, stream>>>(bsum, bbase, rowptr);
    scan3_kernel<<<NB, 256, 0, stream>>>(cnt, bbase, rowptr, cursor);
    fill_kernel<<<cdiv(EE, 256), 256, 0, stream>>>(srcv, tgtv, etype, cursor, csr_src, csr_rel);

    const int ggrid  = cdiv(NN, 128);   // 391
    const int nwgrid = cdiv(NN, 4);

    // ---- projection: h1 = x @ Wp + bp (fp32-effective), + h1b mirror ----
    gemm_mfma<true, false, true, false, true><<<ggrid, 256, 0, stream>>>(
        x, DIN, Wtp_hi, Wtp_lo, DIN, h1, h1b, bp, NN, DIN);

    // ---- RGCN layer 1: h1 -> h2 ----
    rgcn_agg_all8<<<nwgrid, 256, 0, stream>>>(h1b, rowptr, csr_src, csr_rel, aggb);
    gemm_mfma<false, false, false, false, false><<<ggrid, 256, 0, stream>>>(
        aggb, RR * HF, Wt1_hi, Wt1_lo, LDK9, h2, nullptr, nullptr, NN, RR * HF);
    gemm_mfma<true, true, true, true, true><<<ggrid, 256, 0, stream>>>(
        h1, HF, Wt1_hi + 1024, Wt1_lo + 1024, LDK9, h2, h2b, b1, NN, HF);

    // ---- RGCN layer 2: h2 -> h1 ----
    rgcn_agg_all8<<<nwgrid, 256, 0, stream>>>(h2b, rowptr, csr_src, csr_rel, aggb);
    gemm_mfma<false, false, false, false, false><<<ggrid, 256, 0, stream>>>(
        aggb, RR * HF, Wt2_hi, Wt2_lo, LDK9, h1, nullptr, nullptr, NN, RR * HF);
    gemm_mfma<true, true, true, true, true><<<ggrid, 256, 0, stream>>>(
        h2, HF, Wt2_hi + 1024, Wt2_lo + 1024, LDK9, h1, h1b, b2, NN, HF);

    // ---- GAT: z = h1 @ Wg (fp32 z for scores, zb for gather) ----
    gemm_mfma<true, false, false, false, true><<<ggrid, 256, 0, stream>>>(
        h1, HF, Wtg_hi, Wtg_lo, HF, z, zb, nullptr, NN, HF);
    att_scores<<<cdiv((long long)NN * NHEADS, 256), 256, 0, stream>>>(z, att, a_src, a_tgt);
    gat_kernel<<<nwgrid, 256, 0, stream>>>(rowptr, csr_src, a_src, a_tgt, zb, bg, Wf, bf, (float*)d_out);
}

// Round 7
// 663.621 us; speedup vs baseline: 1.3536x; 1.0725x over previous
//
#include <hip/hip_runtime.h>
#include <math.h>

// Problem constants
#define NN      50000
#define EE      800000
#define DIN     256
#define HF      128
#define RR      8
#define NHEADS  8
#define DHH     16
#define OUTC    3
#define M2      (NN * RR)                 // 400000 (t,rel) buckets
#define NB2     ((M2 + 255) / 256)        // 1563 scan blocks
#define CH2     ((NB2 + 255) / 256)       // 7 per-thread chunks in scan2

static inline int cdiv(long long a, int b) { return (int)((a + b - 1) / b); }

typedef __attribute__((ext_vector_type(8))) short short8;
typedef __attribute__((ext_vector_type(4))) float f32x4;

__device__ inline float bf2f(unsigned short u) {
    return __uint_as_float(((unsigned)u) << 16);
}
__device__ inline unsigned short f2bf(float f) {
    unsigned u = __float_as_uint(f);
    u += 0x7fffu + ((u >> 16) & 1u);   // RNE
    return (unsigned short)(u >> 16);
}

// ================= weight transpose + hi/lo split =================
__global__ __launch_bounds__(256) void trans_split_kernel(const float* __restrict__ src,
                                                          unsigned short* __restrict__ dsthi,
                                                          unsigned short* __restrict__ dstlo,
                                                          int K, int k0, int ldk) {
    int i = blockIdx.x * 256 + threadIdx.x;
    if (i >= K * 128) return;
    int k = i >> 7, n = i & 127;
    float f = src[(size_t)k * 128 + n];
    unsigned short hi = f2bf(f);
    unsigned short lo = f2bf(f - bf2f(hi));
    dsthi[(size_t)n * ldk + k0 + k] = hi;
    dstlo[(size_t)n * ldk + k0 + k] = lo;
}

// ================= CSR build, sorted by (tgt, rel) =================
__global__ __launch_bounds__(256) void count2_kernel(const int* __restrict__ tgt,
                                                     const int* __restrict__ et,
                                                     int* __restrict__ cnt2) {
    int i = blockIdx.x * 256 + threadIdx.x;
    if (i < EE) atomicAdd(&cnt2[tgt[i] * RR + et[i]], 1);
}

__global__ __launch_bounds__(256) void scan1_kernel(const int* __restrict__ cnt,
                                                    int* __restrict__ bsum, int n) {
    __shared__ int s[256];
    int t = threadIdx.x;
    int i = blockIdx.x * 256 + t;
    s[t] = (i < n) ? cnt[i] : 0;
    __syncthreads();
    for (int off = 128; off > 0; off >>= 1) {
        if (t < off) s[t] += s[t + off];
        __syncthreads();
    }
    if (t == 0) bsum[blockIdx.x] = s[0];
}

__global__ __launch_bounds__(256) void scan2_kernel(const int* __restrict__ bsum,
                                                    int* __restrict__ bbase,
                                                    int* __restrict__ tail,
                                                    int nb, int ch) {
    __shared__ int s[256];
    int t = threadIdx.x;
    int beg = t * ch;
    int end = beg + ch; if (end > nb) end = nb;
    int sum = 0;
    for (int i = beg; i < end; i++) sum += bsum[i];
    s[t] = sum;
    __syncthreads();
    for (int off = 1; off < 256; off <<= 1) {
        int u = (t >= off) ? s[t - off] : 0;
        __syncthreads();
        s[t] += u;
        __syncthreads();
    }
    int run = s[t] - sum;
    for (int i = beg; i < end; i++) {
        bbase[i] = run;
        run += bsum[i];
    }
    if (t == 255) *tail = s[255];
}

__global__ __launch_bounds__(256) void scan3_kernel(const int* __restrict__ cnt,
                                                    const int* __restrict__ bbase,
                                                    int* __restrict__ rowptr,
                                                    int* __restrict__ cursor, int n) {
    __shared__ int s[256];
    int t = threadIdx.x;
    int i = blockIdx.x * 256 + t;
    int v = (i < n) ? cnt[i] : 0;
    s[t] = v;
    __syncthreads();
    for (int off = 1; off < 256; off <<= 1) {
        int u = (t >= off) ? s[t - off] : 0;
        __syncthreads();
        s[t] += u;
        __syncthreads();
    }
    if (i < n) {
        int e = bbase[blockIdx.x] + s[t] - v;
        rowptr[i] = e;
        cursor[i] = e;
    }
}

__global__ __launch_bounds__(256) void fill2_kernel(const int* __restrict__ src,
                                                    const int* __restrict__ tgt,
                                                    const int* __restrict__ et,
                                                    int* __restrict__ cursor2,
                                                    int* __restrict__ csr_src2) {
    int e = blockIdx.x * 256 + threadIdx.x;
    if (e >= EE) return;
    int pos = atomicAdd(&cursor2[tgt[e] * RR + et[e]], 1);
    csr_src2[pos] = src[e];
}

// ================= generic MFMA GEMM (projection): C=A@Bt, A fp32 split, bias, bf16 mirror =================
#define BK 32
#define APAD 36

template <bool SPLITA, bool ACC, bool BIAS, bool RELU, bool BF16OUT>
__global__ __launch_bounds__(256) void gemm_mfma(const void* __restrict__ Av, int lda,
                                                 const unsigned short* __restrict__ Bthi,
                                                 const unsigned short* __restrict__ Btlo, int ldk,
                                                 float* __restrict__ C,
                                                 unsigned short* __restrict__ Cb,
                                                 const float* __restrict__ bias,
                                                 int M, int K) {
    __shared__ unsigned short Ah[128 * APAD];
    __shared__ unsigned short Al[(SPLITA ? 128 : 1) * APAD];
    __shared__ unsigned short Bh[128 * APAD];
    __shared__ unsigned short Bl[128 * APAD];
    const int tid  = threadIdx.x;
    const int m0   = blockIdx.x * 128;
    const int w    = tid >> 6;
    const int lane = tid & 63;
    const int lrow = lane & 15;
    const int q    = lane >> 4;

    f32x4 acc[2][8];
#pragma unroll
    for (int t = 0; t < 2; t++)
#pragma unroll
        for (int c = 0; c < 8; c++) acc[t][c] = (f32x4){0.f, 0.f, 0.f, 0.f};

    const int srow  = tid >> 1;
    const int spart = (tid & 1) * 16;

    for (int k0 = 0; k0 < K; k0 += BK) {
        if (SPLITA) {
            const float* A = (const float*)Av;
            int gm = m0 + srow;
            float va[16];
            if (gm < M) {
                const float* ap = &A[(size_t)gm * lda + k0 + spart];
#pragma unroll
                for (int j = 0; j < 4; j++) {
                    float4 v = *reinterpret_cast<const float4*>(ap + j * 4);
                    va[j * 4 + 0] = v.x; va[j * 4 + 1] = v.y; va[j * 4 + 2] = v.z; va[j * 4 + 3] = v.w;
                }
            } else {
#pragma unroll
                for (int j = 0; j < 16; j++) va[j] = 0.f;
            }
            unsigned hw[8], lw[8];
#pragma unroll
            for (int j = 0; j < 8; j++) {
                unsigned short h0 = f2bf(va[2 * j]);
                unsigned short h1 = f2bf(va[2 * j + 1]);
                unsigned short l0 = f2bf(va[2 * j] - bf2f(h0));
                unsigned short l1 = f2bf(va[2 * j + 1] - bf2f(h1));
                hw[j] = (unsigned)h0 | ((unsigned)h1 << 16);
                lw[j] = (unsigned)l0 | ((unsigned)l1 << 16);
            }
            *reinterpret_cast<uint4*>(&Ah[srow * APAD + spart])     = make_uint4(hw[0], hw[1], hw[2], hw[3]);
            *reinterpret_cast<uint4*>(&Ah[srow * APAD + spart + 8]) = make_uint4(hw[4], hw[5], hw[6], hw[7]);
            *reinterpret_cast<uint4*>(&Al[srow * APAD + spart])     = make_uint4(lw[0], lw[1], lw[2], lw[3]);
            *reinterpret_cast<uint4*>(&Al[srow * APAD + spart + 8]) = make_uint4(lw[4], lw[5], lw[6], lw[7]);
        } else {
            const unsigned short* A = (const unsigned short*)Av;
            int gm = m0 + srow;
            uint4 v  = make_uint4(0u, 0u, 0u, 0u);
            uint4 v2 = make_uint4(0u, 0u, 0u, 0u);
            if (gm < M) {
                const unsigned short* ap = &A[(size_t)gm * lda + k0 + spart];
                v  = *reinterpret_cast<const uint4*>(ap);
                v2 = *reinterpret_cast<const uint4*>(ap + 8);
            }
            *reinterpret_cast<uint4*>(&Ah[srow * APAD + spart])     = v;
            *reinterpret_cast<uint4*>(&Ah[srow * APAD + spart + 8]) = v2;
        }
        {
            const unsigned short* bh = &Bthi[(size_t)srow * ldk + k0 + spart];
            const unsigned short* bl = &Btlo[(size_t)srow * ldk + k0 + spart];
            *reinterpret_cast<uint4*>(&Bh[srow * APAD + spart])     = *reinterpret_cast<const uint4*>(bh);
            *reinterpret_cast<uint4*>(&Bh[srow * APAD + spart + 8]) = *reinterpret_cast<const uint4*>(bh + 8);
            *reinterpret_cast<uint4*>(&Bl[srow * APAD + spart])     = *reinterpret_cast<const uint4*>(bl);
            *reinterpret_cast<uint4*>(&Bl[srow * APAD + spart + 8]) = *reinterpret_cast<const uint4*>(bl + 8);
        }
        __syncthreads();

        short8 ah[2], al[2];
#pragma unroll
        for (int t = 0; t < 2; t++) {
            ah[t] = *reinterpret_cast<const short8*>(&Ah[(w * 32 + t * 16 + lrow) * APAD + q * 8]);
            if (SPLITA)
                al[t] = *reinterpret_cast<const short8*>(&Al[(w * 32 + t * 16 + lrow) * APAD + q * 8]);
        }
#pragma unroll
        for (int c = 0; c < 8; c++) {
            short8 bh = *reinterpret_cast<const short8*>(&Bh[(c * 16 + lrow) * APAD + q * 8]);
            short8 bl = *reinterpret_cast<const short8*>(&Bl[(c * 16 + lrow) * APAD + q * 8]);
#pragma unroll
            for (int t = 0; t < 2; t++) {
                acc[t][c] = __builtin_amdgcn_mfma_f32_16x16x32_bf16(ah[t], bl, acc[t][c], 0, 0, 0);
                if (SPLITA)
                    acc[t][c] = __builtin_amdgcn_mfma_f32_16x16x32_bf16(al[t], bh, acc[t][c], 0, 0, 0);
                acc[t][c] = __builtin_amdgcn_mfma_f32_16x16x32_bf16(ah[t], bh, acc[t][c], 0, 0, 0);
            }
        }
        __syncthreads();
    }

#pragma unroll
    for (int t = 0; t < 2; t++) {
#pragma unroll
        for (int r = 0; r < 4; r++) {
            int gm = m0 + w * 32 + t * 16 + q * 4 + r;
            if (gm >= M) continue;
#pragma unroll
            for (int c = 0; c < 8; c++) {
                int gn = c * 16 + lrow;
                float v = acc[t][c][r];
                if (BIAS) v += bias[gn];
                if (ACC)  v += C[(size_t)gm * HF + gn];
                if (RELU) v = fmaxf(v, 0.f);
                C[(size_t)gm * HF + gn] = v;
                if (BF16OUT) Cb[(size_t)gm * HF + gn] = f2bf(v);
            }
        }
    }
}

// ================= merged RGCN layer GEMM =================
// hout = relu( aggb[N,1024] @ W[0:1024]^T + hin[N,128] @ root^T + bias ), + bf16 mirror.
// Phase 1: bf16 A (2 MFMAs); phase 2: fp32 A split (3 MFMAs). Wt has ldk = 1152.
__global__ __launch_bounds__(256) void gemm_rgcn(const unsigned short* __restrict__ aggb,
                                                 const float* __restrict__ hin,
                                                 const unsigned short* __restrict__ Bthi,
                                                 const unsigned short* __restrict__ Btlo,
                                                 float* __restrict__ hout,
                                                 unsigned short* __restrict__ hbout,
                                                 const float* __restrict__ bias, int M) {
    const int LDK = (RR + 1) * HF;  // 1152
    __shared__ unsigned short Ah[128 * APAD];
    __shared__ unsigned short Al[128 * APAD];
    __shared__ unsigned short Bh[128 * APAD];
    __shared__ unsigned short Bl[128 * APAD];
    const int tid  = threadIdx.x;
    const int m0   = blockIdx.x * 128;
    const int w    = tid >> 6;
    const int lane = tid & 63;
    const int lrow = lane & 15;
    const int q    = lane >> 4;

    f32x4 acc[2][8];
#pragma unroll
    for (int t = 0; t < 2; t++)
#pragma unroll
        for (int c = 0; c < 8; c++) acc[t][c] = (f32x4){0.f, 0.f, 0.f, 0.f};

    const int srow  = tid >> 1;
    const int spart = (tid & 1) * 16;

    // ---- phase 1: K = 0..1024, A = aggb (bf16) ----
    for (int k0 = 0; k0 < RR * HF; k0 += BK) {
        {
            int gm = m0 + srow;
            uint4 v  = make_uint4(0u, 0u, 0u, 0u);
            uint4 v2 = make_uint4(0u, 0u, 0u, 0u);
            if (gm < M) {
                const unsigned short* ap = &aggb[(size_t)gm * (RR * HF) + k0 + spart];
                v  = *reinterpret_cast<const uint4*>(ap);
                v2 = *reinterpret_cast<const uint4*>(ap + 8);
            }
            *reinterpret_cast<uint4*>(&Ah[srow * APAD + spart])     = v;
            *reinterpret_cast<uint4*>(&Ah[srow * APAD + spart + 8]) = v2;
        }
        {
            const unsigned short* bh = &Bthi[(size_t)srow * LDK + k0 + spart];
            const unsigned short* bl = &Btlo[(size_t)srow * LDK + k0 + spart];
            *reinterpret_cast<uint4*>(&Bh[srow * APAD + spart])     = *reinterpret_cast<const uint4*>(bh);
            *reinterpret_cast<uint4*>(&Bh[srow * APAD + spart + 8]) = *reinterpret_cast<const uint4*>(bh + 8);
            *reinterpret_cast<uint4*>(&Bl[srow * APAD + spart])     = *reinterpret_cast<const uint4*>(bl);
            *reinterpret_cast<uint4*>(&Bl[srow * APAD + spart + 8]) = *reinterpret_cast<const uint4*>(bl + 8);
        }
        __syncthreads();
        short8 ah[2];
#pragma unroll
        for (int t = 0; t < 2; t++)
            ah[t] = *reinterpret_cast<const short8*>(&Ah[(w * 32 + t * 16 + lrow) * APAD + q * 8]);
#pragma unroll
        for (int c = 0; c < 8; c++) {
            short8 bh = *reinterpret_cast<const short8*>(&Bh[(c * 16 + lrow) * APAD + q * 8]);
            short8 bl = *reinterpret_cast<const short8*>(&Bl[(c * 16 + lrow) * APAD + q * 8]);
#pragma unroll
            for (int t = 0; t < 2; t++) {
                acc[t][c] = __builtin_amdgcn_mfma_f32_16x16x32_bf16(ah[t], bl, acc[t][c], 0, 0, 0);
                acc[t][c] = __builtin_amdgcn_mfma_f32_16x16x32_bf16(ah[t], bh, acc[t][c], 0, 0, 0);
            }
        }
        __syncthreads();
    }

    // ---- phase 2: K = 1024..1152, A = hin (fp32 split) ----
    for (int k0 = 0; k0 < HF; k0 += BK) {
        {
            int gm = m0 + srow;
            float va[16];
            if (gm < M) {
                const float* ap = &hin[(size_t)gm * HF + k0 + spart];
#pragma unroll
                for (int j = 0; j < 4; j++) {
                    float4 v = *reinterpret_cast<const float4*>(ap + j * 4);
                    va[j * 4 + 0] = v.x; va[j * 4 + 1] = v.y; va[j * 4 + 2] = v.z; va[j * 4 + 3] = v.w;
                }
            } else {
#pragma unroll
                for (int j = 0; j < 16; j++) va[j] = 0.f;
            }
            unsigned hw[8], lw[8];
#pragma unroll
            for (int j = 0; j < 8; j++) {
                unsigned short h0 = f2bf(va[2 * j]);
                unsigned short h1 = f2bf(va[2 * j + 1]);
                unsigned short l0 = f2bf(va[2 * j] - bf2f(h0));
                unsigned short l1 = f2bf(va[2 * j + 1] - bf2f(h1));
                hw[j] = (unsigned)h0 | ((unsigned)h1 << 16);
                lw[j] = (unsigned)l0 | ((unsigned)l1 << 16);
            }
            *reinterpret_cast<uint4*>(&Ah[srow * APAD + spart])     = make_uint4(hw[0], hw[1], hw[2], hw[3]);
            *reinterpret_cast<uint4*>(&Ah[srow * APAD + spart + 8]) = make_uint4(hw[4], hw[5], hw[6], hw[7]);
            *reinterpret_cast<uint4*>(&Al[srow * APAD + spart])     = make_uint4(lw[0], lw[1], lw[2], lw[3]);
            *reinterpret_cast<uint4*>(&Al[srow * APAD + spart + 8]) = make_uint4(lw[4], lw[5], lw[6], lw[7]);
        }
        {
            const unsigned short* bh = &Bthi[(size_t)srow * LDK + RR * HF + k0 + spart];
            const unsigned short* bl = &Btlo[(size_t)srow * LDK + RR * HF + k0 + spart];
            *reinterpret_cast<uint4*>(&Bh[srow * APAD + spart])     = *reinterpret_cast<const uint4*>(bh);
            *reinterpret_cast<uint4*>(&Bh[srow * APAD + spart + 8]) = *reinterpret_cast<const uint4*>(bh + 8);
            *reinterpret_cast<uint4*>(&Bl[srow * APAD + spart])     = *reinterpret_cast<const uint4*>(bl);
            *reinterpret_cast<uint4*>(&Bl[srow * APAD + spart + 8]) = *reinterpret_cast<const uint4*>(bl + 8);
        }
        __syncthreads();
        short8 ah[2], al[2];
#pragma unroll
        for (int t = 0; t < 2; t++) {
            ah[t] = *reinterpret_cast<const short8*>(&Ah[(w * 32 + t * 16 + lrow) * APAD + q * 8]);
            al[t] = *reinterpret_cast<const short8*>(&Al[(w * 32 + t * 16 + lrow) * APAD + q * 8]);
        }
#pragma unroll
        for (int c = 0; c < 8; c++) {
            short8 bh = *reinterpret_cast<const short8*>(&Bh[(c * 16 + lrow) * APAD + q * 8]);
            short8 bl = *reinterpret_cast<const short8*>(&Bl[(c * 16 + lrow) * APAD + q * 8]);
#pragma unroll
            for (int t = 0; t < 2; t++) {
                acc[t][c] = __builtin_amdgcn_mfma_f32_16x16x32_bf16(ah[t], bl, acc[t][c], 0, 0, 0);
                acc[t][c] = __builtin_amdgcn_mfma_f32_16x16x32_bf16(al[t], bh, acc[t][c], 0, 0, 0);
                acc[t][c] = __builtin_amdgcn_mfma_f32_16x16x32_bf16(ah[t], bh, acc[t][c], 0, 0, 0);
            }
        }
        __syncthreads();
    }

#pragma unroll
    for (int t = 0; t < 2; t++) {
#pragma unroll
        for (int r = 0; r < 4; r++) {
            int gm = m0 + w * 32 + t * 16 + q * 4 + r;
            if (gm >= M) continue;
#pragma unroll
            for (int c = 0; c < 8; c++) {
                int gn = c * 16 + lrow;
                float v = fmaxf(acc[t][c][r] + bias[gn], 0.f);
                hout[(size_t)gm * HF + gn] = v;
                hbout[(size_t)gm * HF + gn] = f2bf(v);
            }
        }
    }
}

// ================= z GEMM with fused attention scores =================
// zb[N,128](bf16) = h @ Wg^T (fp32-effective); a_src/a_tgt[N,8] from fp32 accumulators.
__global__ __launch_bounds__(256) void gemm_z(const float* __restrict__ hin,
                                              const unsigned short* __restrict__ Bthi,
                                              const unsigned short* __restrict__ Btlo,
                                              const float* __restrict__ att,
                                              unsigned short* __restrict__ zb,
                                              float* __restrict__ a_src,
                                              float* __restrict__ a_tgt, int M) {
    __shared__ unsigned short Ah[128 * APAD];
    __shared__ unsigned short Al[128 * APAD];
    __shared__ unsigned short Bh[128 * APAD];
    __shared__ unsigned short Bl[128 * APAD];
    const int tid  = threadIdx.x;
    const int m0   = blockIdx.x * 128;
    const int w    = tid >> 6;
    const int lane = tid & 63;
    const int lrow = lane & 15;
    const int q    = lane >> 4;

    f32x4 acc[2][8];
#pragma unroll
    for (int t = 0; t < 2; t++)
#pragma unroll
        for (int c = 0; c < 8; c++) acc[t][c] = (f32x4){0.f, 0.f, 0.f, 0.f};

    const int srow  = tid >> 1;
    const int spart = (tid & 1) * 16;

    for (int k0 = 0; k0 < HF; k0 += BK) {
        {
            int gm = m0 + srow;
            float va[16];
            if (gm < M) {
                const float* ap = &hin[(size_t)gm * HF + k0 + spart];
#pragma unroll
                for (int j = 0; j < 4; j++) {
                    float4 v = *reinterpret_cast<const float4*>(ap + j * 4);
                    va[j * 4 + 0] = v.x; va[j * 4 + 1] = v.y; va[j * 4 + 2] = v.z; va[j * 4 + 3] = v.w;
                }
            } else {
#pragma unroll
                for (int j = 0; j < 16; j++) va[j] = 0.f;
            }
            unsigned hw[8], lw[8];
#pragma unroll
            for (int j = 0; j < 8; j++) {
                unsigned short h0 = f2bf(va[2 * j]);
                unsigned short h1 = f2bf(va[2 * j + 1]);
                unsigned short l0 = f2bf(va[2 * j] - bf2f(h0));
                unsigned short l1 = f2bf(va[2 * j + 1] - bf2f(h1));
                hw[j] = (unsigned)h0 | ((unsigned)h1 << 16);
                lw[j] = (unsigned)l0 | ((unsigned)l1 << 16);
            }
            *reinterpret_cast<uint4*>(&Ah[srow * APAD + spart])     = make_uint4(hw[0], hw[1], hw[2], hw[3]);
            *reinterpret_cast<uint4*>(&Ah[srow * APAD + spart + 8]) = make_uint4(hw[4], hw[5], hw[6], hw[7]);
            *reinterpret_cast<uint4*>(&Al[srow * APAD + spart])     = make_uint4(lw[0], lw[1], lw[2], lw[3]);
            *reinterpret_cast<uint4*>(&Al[srow * APAD + spart + 8]) = make_uint4(lw[4], lw[5], lw[6], lw[7]);
        }
        {
            const unsigned short* bh = &Bthi[(size_t)srow * HF + k0 + spart];
            const unsigned short* bl = &Btlo[(size_t)srow * HF + k0 + spart];
            *reinterpret_cast<uint4*>(&Bh[srow * APAD + spart])     = *reinterpret_cast<const uint4*>(bh);
            *reinterpret_cast<uint4*>(&Bh[srow * APAD + spart + 8]) = *reinterpret_cast<const uint4*>(bh + 8);
            *reinterpret_cast<uint4*>(&Bl[srow * APAD + spart])     = *reinterpret_cast<const uint4*>(bl);
            *reinterpret_cast<uint4*>(&Bl[srow * APAD + spart + 8]) = *reinterpret_cast<const uint4*>(bl + 8);
        }
        __syncthreads();
        short8 ah[2], al[2];
#pragma unroll
        for (int t = 0; t < 2; t++) {
            ah[t] = *reinterpret_cast<const short8*>(&Ah[(w * 32 + t * 16 + lrow) * APAD + q * 8]);
            al[t] = *reinterpret_cast<const short8*>(&Al[(w * 32 + t * 16 + lrow) * APAD + q * 8]);
        }
#pragma unroll
        for (int c = 0; c < 8; c++) {
            short8 bh = *reinterpret_cast<const short8*>(&Bh[(c * 16 + lrow) * APAD + q * 8]);
            short8 bl = *reinterpret_cast<const short8*>(&Bl[(c * 16 + lrow) * APAD + q * 8]);
#pragma unroll
            for (int t = 0; t < 2; t++) {
                acc[t][c] = __builtin_amdgcn_mfma_f32_16x16x32_bf16(ah[t], bl, acc[t][c], 0, 0, 0);
                acc[t][c] = __builtin_amdgcn_mfma_f32_16x16x32_bf16(al[t], bh, acc[t][c], 0, 0, 0);
                acc[t][c] = __builtin_amdgcn_mfma_f32_16x16x32_bf16(ah[t], bh, acc[t][c], 0, 0, 0);
            }
        }
        __syncthreads();
    }

    // per-lane att coefficients for all 8 heads at this lrow
    float att_s[8], att_t[8];
#pragma unroll
    for (int c = 0; c < 8; c++) {
        att_s[c] = att[c * 32 + lrow];
        att_t[c] = att[c * 32 + 16 + lrow];
    }

#pragma unroll
    for (int t = 0; t < 2; t++) {
#pragma unroll
        for (int r = 0; r < 4; r++) {
            int gm = m0 + w * 32 + t * 16 + q * 4 + r;
            if (gm >= M) continue;
#pragma unroll
            for (int c = 0; c < 8; c++) {
                int gn = c * 16 + lrow;
                float v = acc[t][c][r];
                zb[(size_t)gm * HF + gn] = f2bf(v);
                float ps = v * att_s[c];
                float pt = v * att_t[c];
#pragma unroll
                for (int off = 1; off < 16; off <<= 1) {
                    ps += __shfl_xor(ps, off);
                    pt += __shfl_xor(pt, off);
                }
                if (lrow == 0) {
                    a_src[(size_t)gm * NHEADS + c] = ps;
                    a_tgt[(size_t)gm * NHEADS + c] = pt;
                }
            }
        }
    }
}

// ================= RGCN gather: (tgt,rel)-sorted segments, bf16 in/out =================
__global__ __launch_bounds__(256) void rgcn_agg_sorted(const unsigned short* __restrict__ hb,
                                                       const int* __restrict__ rowptr2,
                                                       const int* __restrict__ csr_src2,
                                                       unsigned short* __restrict__ agg) {
    int w = (blockIdx.x * 256 + threadIdx.x) >> 6;
    if (w >= NN) return;
    int lane = threadIdx.x & 63;
    int c0 = lane * 2;
    const int b8 = w * RR;
    unsigned short* o = &agg[(size_t)w * (RR * HF)];
    int b = rowptr2[b8];
#pragma unroll
    for (int r = 0; r < RR; r++) {
        int e2 = rowptr2[b8 + r + 1];
        float ax = 0.f, ay = 0.f;
        for (int e = b; e < e2; e++) {
            int s = csr_src2[e];
            unsigned hv = *reinterpret_cast<const unsigned*>(&hb[(size_t)s * HF + c0]);
            ax += bf2f((unsigned short)(hv & 0xffffu));
            ay += bf2f((unsigned short)(hv >> 16));
        }
        int n = e2 - b;
        float inv = 1.f / (float)(n > 1 ? n : 1);
        unsigned packed = (unsigned)f2bf(ax * inv) | ((unsigned)f2bf(ay * inv) << 16);
        *reinterpret_cast<unsigned*>(&o[r * HF + c0]) = packed;
        b = e2;
    }
}

// ================= GAT: wave/node online softmax (zb bf16) + Wf GEMV + log_softmax =================
__global__ __launch_bounds__(256) void gat_kernel(const int* __restrict__ rowptr2,
                                                  const int* __restrict__ csr_src2,
                                                  const float* __restrict__ a_src,
                                                  const float* __restrict__ a_tgt,
                                                  const unsigned short* __restrict__ zb,
                                                  const float* __restrict__ bg,
                                                  const float* __restrict__ Wf,
                                                  const float* __restrict__ bf,
                                                  float* __restrict__ out) {
    int w = (blockIdx.x * 256 + threadIdx.x) >> 6;
    if (w >= NN) return;
    int lane = threadIdx.x & 63;
    int hd = lane >> 3;
    int c0 = lane * 2;
    float at = a_tgt[w * NHEADS + hd];
    int beg = rowptr2[w * RR], end = rowptr2[w * RR + RR];

    float m = -1e30f, l = 0.f;
    float ax = 0.f, ay = 0.f;
    for (int e = beg; e < end; e++) {
        int s = csr_src2[e];
        float a = a_src[s * NHEADS + hd] + at;
        a = a > 0.f ? a : 0.2f * a;
        float mn = fmaxf(m, a);
        float sc  = __expf(m - mn);
        float wgt = __expf(a - mn);
        l = l * sc + wgt;
        unsigned zv = *reinterpret_cast<const unsigned*>(&zb[(size_t)s * HF + c0]);
        ax = ax * sc + bf2f((unsigned short)(zv & 0xffffu)) * wgt;
        ay = ay * sc + bf2f((unsigned short)(zv >> 16)) * wgt;
        m = mn;
    }
    float inv = 1.f / fmaxf(l, 1e-16f);
    float vx = ax * inv + bg[c0];
    float vy = ay * inv + bg[c0 + 1];

    float p0 = vx * Wf[c0 * 3 + 0] + vy * Wf[(c0 + 1) * 3 + 0];
    float p1 = vx * Wf[c0 * 3 + 1] + vy * Wf[(c0 + 1) * 3 + 1];
    float p2 = vx * Wf[c0 * 3 + 2] + vy * Wf[(c0 + 1) * 3 + 2];
#pragma unroll
    for (int off = 32; off > 0; off >>= 1) {
        p0 += __shfl_xor(p0, off);
        p1 += __shfl_xor(p1, off);
        p2 += __shfl_xor(p2, off);
    }
    if (lane == 0) {
        float l0 = p0 + bf[0], l1 = p1 + bf[1], l2 = p2 + bf[2];
        float mm = fmaxf(l0, fmaxf(l1, l2));
        float lse = mm + logf(expf(l0 - mm) + expf(l1 - mm) + expf(l2 - mm));
        out[(size_t)w * 3 + 0] = l0 - lse;
        out[(size_t)w * 3 + 1] = l1 - lse;
        out[(size_t)w * 3 + 2] = l2 - lse;
    }
}

// ================= launch =================
extern "C" void kernel_launch(void* const* d_in, const int* in_sizes, int n_in,
                              void* d_out, int out_size, void* d_ws, size_t ws_size,
                              hipStream_t stream) {
    const float* x     = (const float*)d_in[0];
    const int*   ei    = (const int*)d_in[1];
    const int*   etype = (const int*)d_in[2];
    const float* Wp    = (const float*)d_in[3];
    const float* bp    = (const float*)d_in[4];
    const float* W1    = (const float*)d_in[5];
    const float* root1 = (const float*)d_in[6];
    const float* b1    = (const float*)d_in[7];
    const float* W2    = (const float*)d_in[8];
    const float* root2 = (const float*)d_in[9];
    const float* b2    = (const float*)d_in[10];
    const float* Wg    = (const float*)d_in[11];
    const float* att   = (const float*)d_in[12];
    const float* bg    = (const float*)d_in[13];
    const float* Wf    = (const float*)d_in[14];
    const float* bf    = (const float*)d_in[15];
    (void)in_sizes; (void)n_in; (void)out_size; (void)ws_size;

    const int* srcv = ei;
    const int* tgtv = ei + EE;

    const int LDK9 = (RR + 1) * HF;  // 1152

    // ---- workspace layout (bytes), ~185.4 MB ----
    char* base = (char*)d_ws;
    unsigned short* aggb = (unsigned short*)(base + 0);   // N*1024*2 = 102,400,000
    // CSR-build scratch aliased into aggb (dead before first walk):
    int* cnt2    = (int*)(base + 96000000);               // 1,600,000
    int* cursor2 = (int*)(base + 98000000);               // 1,600,000
    int* bsum2   = (int*)(base + 99700000);               // 6,256
    int* bbase2  = (int*)(base + 99800000);               // 6,256
    // GAT-phase aliases into aggb (dead after layer-2 GEMM):
    unsigned short* zb = (unsigned short*)(base + 0);     // 12,800,000
    float* a_src = (float*)(base + 12800000);             // 1,600,000
    float* a_tgt = (float*)(base + 14400000);             // 1,600,000
    float* h1    = (float*)(base + 102400000);            // 25,600,000
    float* h2    = (float*)(base + 128000000);            // 25,600,000
    unsigned short* h1b = (unsigned short*)(base + 153600000); // 12,800,000
    unsigned short* h2b = (unsigned short*)(base + 166400000); // 12,800,000
    int* csr_src2 = (int*)(base + 179200000);             // 3,200,000
    int* rowptr2  = (int*)(base + 182400000);             // (M2+1)*4 -> 1,600,016
    unsigned short* Wtp_hi = (unsigned short*)(base + 184000016); // 65,536
    unsigned short* Wtp_lo = (unsigned short*)(base + 184065552); // 65,536
    unsigned short* Wt1_hi = (unsigned short*)(base + 184131088); // 294,912
    unsigned short* Wt1_lo = (unsigned short*)(base + 184426000); // 294,912
    unsigned short* Wt2_hi = (unsigned short*)(base + 184720912); // 294,912
    unsigned short* Wt2_lo = (unsigned short*)(base + 185015824); // 294,912
    unsigned short* Wtg_hi = (unsigned short*)(base + 185310736); // 32,768
    unsigned short* Wtg_lo = (unsigned short*)(base + 185343504); // 32,768

    // ---- weight prep ----
    trans_split_kernel<<<cdiv(256 * 128, 256), 256, 0, stream>>>(Wp, Wtp_hi, Wtp_lo, 256, 0, 256);
    trans_split_kernel<<<cdiv(1024 * 128, 256), 256, 0, stream>>>(W1, Wt1_hi, Wt1_lo, 1024, 0, LDK9);
    trans_split_kernel<<<cdiv(128 * 128, 256), 256, 0, stream>>>(root1, Wt1_hi, Wt1_lo, 128, 1024, LDK9);
    trans_split_kernel<<<cdiv(1024 * 128, 256), 256, 0, stream>>>(W2, Wt2_hi, Wt2_lo, 1024, 0, LDK9);
    trans_split_kernel<<<cdiv(128 * 128, 256), 256, 0, stream>>>(root2, Wt2_hi, Wt2_lo, 128, 1024, LDK9);
    trans_split_kernel<<<cdiv(128 * 128, 256), 256, 0, stream>>>(Wg, Wtg_hi, Wtg_lo, 128, 0, 128);

    // ---- CSR build, sorted by (tgt, rel) ----
    hipMemsetAsync(cnt2, 0, (size_t)M2 * 4, stream);
    count2_kernel<<<cdiv(EE, 256), 256, 0, stream>>>(tgtv, etype, cnt2);
    scan1_kernel<<<NB2, 256, 0, stream>>>(cnt2, bsum2, M2);
    scan2_kernel<<<1, 256, 0, stream>>>(bsum2, bbase2, &rowptr2[M2], NB2, CH2);
    scan3_kernel<<<NB2, 256, 0, stream>>>(cnt2, bbase2, rowptr2, cursor2, M2);
    fill2_kernel<<<cdiv(EE, 256), 256, 0, stream>>>(srcv, tgtv, etype, cursor2, csr_src2);

    const int ggrid  = cdiv(NN, 128);   // 391
    const int nwgrid = cdiv(NN, 4);

    // ---- projection: h1 = x @ Wp + bp (fp32-effective) + h1b mirror ----
    gemm_mfma<true, false, true, false, true><<<ggrid, 256, 0, stream>>>(
        x, DIN, Wtp_hi, Wtp_lo, DIN, h1, h1b, bp, NN, DIN);

    // ---- RGCN layer 1: h1 -> h2 ----
    rgcn_agg_sorted<<<nwgrid, 256, 0, stream>>>(h1b, rowptr2, csr_src2, aggb);
    gemm_rgcn<<<ggrid, 256, 0, stream>>>(aggb, h1, Wt1_hi, Wt1_lo, h2, h2b, b1, NN);

    // ---- RGCN layer 2: h2 -> h1 ----
    rgcn_agg_sorted<<<nwgrid, 256, 0, stream>>>(h2b, rowptr2, csr_src2, aggb);
    gemm_rgcn<<<ggrid, 256, 0, stream>>>(aggb, h2, Wt2_hi, Wt2_lo, h1, h1b, b2, NN);

    // ---- GAT: z GEMM (fused scores) + softmax-aggregate ----
    gemm_z<<<ggrid, 256, 0, stream>>>(h1, Wtg_hi, Wtg_lo, att, zb, a_src, a_tgt, NN);
    gat_kernel<<<nwgrid, 256, 0, stream>>>(rowptr2, csr_src2, a_src, a_tgt, zb, bg, Wf, bf, (float*)d_out);
}

// Round 8
// 595.708 us; speedup vs baseline: 1.5079x; 1.1140x over previous
//
#include <hip/hip_runtime.h>
#include <math.h>

// Problem constants
#define NN      50000
#define EE      800000
#define DIN     256
#define HF      128
#define RR      8
#define NHEADS  8
#define DHH     16
#define OUTC    3
#define M2      (NN * RR)                 // 400000 (t,rel) buckets
#define NB2     ((M2 + 255) / 256)        // 1563 scan blocks
#define CH2     ((NB2 + 255) / 256)       // 7 per-thread chunks in scan2

static inline int cdiv(long long a, int b) { return (int)((a + b - 1) / b); }

typedef __attribute__((ext_vector_type(8))) short short8;
typedef __attribute__((ext_vector_type(4))) float f32x4;

__device__ inline float bf2f(unsigned short u) {
    return __uint_as_float(((unsigned)u) << 16);
}
__device__ inline unsigned short f2bf(float f) {
    unsigned u = __float_as_uint(f);
    u += 0x7fffu + ((u >> 16) & 1u);   // RNE
    return (unsigned short)(u >> 16);
}

// ================= fused weight prep: transpose + hi/lo split, one dispatch =================
// regions (flat idx): Wp[0,32768) | W1[32768,163840) | root1[163840,180224)
//                     | W2[180224,311296) | root2[311296,327680) | Wg[327680,344064)
__global__ __launch_bounds__(256) void prep_weights(const float* __restrict__ Wp,
                                                    const float* __restrict__ W1,
                                                    const float* __restrict__ root1,
                                                    const float* __restrict__ W2,
                                                    const float* __restrict__ root2,
                                                    const float* __restrict__ Wg,
                                                    unsigned short* __restrict__ Wtp_hi,
                                                    unsigned short* __restrict__ Wtp_lo,
                                                    unsigned short* __restrict__ Wt1_hi,
                                                    unsigned short* __restrict__ Wt1_lo,
                                                    unsigned short* __restrict__ Wt2_hi,
                                                    unsigned short* __restrict__ Wt2_lo,
                                                    unsigned short* __restrict__ Wtg_hi,
                                                    unsigned short* __restrict__ Wtg_lo) {
    int i = blockIdx.x * 256 + threadIdx.x;
    if (i >= 344064) return;
    const float* src; unsigned short *dh, *dl; int k0, ldk, base;
    if (i < 32768)       { src = Wp;    dh = Wtp_hi; dl = Wtp_lo; k0 = 0;    ldk = 256;  base = 0; }
    else if (i < 163840) { src = W1;    dh = Wt1_hi; dl = Wt1_lo; k0 = 0;    ldk = 1152; base = 32768; }
    else if (i < 180224) { src = root1; dh = Wt1_hi; dl = Wt1_lo; k0 = 1024; ldk = 1152; base = 163840; }
    else if (i < 311296) { src = W2;    dh = Wt2_hi; dl = Wt2_lo; k0 = 0;    ldk = 1152; base = 180224; }
    else if (i < 327680) { src = root2; dh = Wt2_hi; dl = Wt2_lo; k0 = 1024; ldk = 1152; base = 311296; }
    else                 { src = Wg;    dh = Wtg_hi; dl = Wtg_lo; k0 = 0;    ldk = 128;  base = 327680; }
    int j = i - base;
    int k = j >> 7, n = j & 127;
    float f = src[(size_t)k * 128 + n];
    unsigned short hi = f2bf(f);
    unsigned short lo = f2bf(f - bf2f(hi));
    dh[(size_t)n * ldk + k0 + k] = hi;
    dl[(size_t)n * ldk + k0 + k] = lo;
}

// ================= CSR build, sorted by (tgt, rel) =================
__global__ __launch_bounds__(256) void count2_kernel(const int* __restrict__ tgt,
                                                     const int* __restrict__ et,
                                                     int* __restrict__ cnt2) {
    int i = blockIdx.x * 256 + threadIdx.x;
    if (i < EE) atomicAdd(&cnt2[tgt[i] * RR + et[i]], 1);
}

__global__ __launch_bounds__(256) void scan1_kernel(const int* __restrict__ cnt,
                                                    int* __restrict__ bsum, int n) {
    __shared__ int s[256];
    int t = threadIdx.x;
    int i = blockIdx.x * 256 + t;
    s[t] = (i < n) ? cnt[i] : 0;
    __syncthreads();
    for (int off = 128; off > 0; off >>= 1) {
        if (t < off) s[t] += s[t + off];
        __syncthreads();
    }
    if (t == 0) bsum[blockIdx.x] = s[0];
}

__global__ __launch_bounds__(256) void scan2_kernel(const int* __restrict__ bsum,
                                                    int* __restrict__ bbase,
                                                    int* __restrict__ tail,
                                                    int nb, int ch) {
    __shared__ int s[256];
    int t = threadIdx.x;
    int beg = t * ch;
    int end = beg + ch; if (end > nb) end = nb;
    int sum = 0;
    for (int i = beg; i < end; i++) sum += bsum[i];
    s[t] = sum;
    __syncthreads();
    for (int off = 1; off < 256; off <<= 1) {
        int u = (t >= off) ? s[t - off] : 0;
        __syncthreads();
        s[t] += u;
        __syncthreads();
    }
    int run = s[t] - sum;
    for (int i = beg; i < end; i++) {
        bbase[i] = run;
        run += bsum[i];
    }
    if (t == 255) *tail = s[255];
}

__global__ __launch_bounds__(256) void scan3_kernel(const int* __restrict__ cnt,
                                                    const int* __restrict__ bbase,
                                                    int* __restrict__ rowptr,
                                                    int* __restrict__ cursor, int n) {
    __shared__ int s[256];
    int t = threadIdx.x;
    int i = blockIdx.x * 256 + t;
    int v = (i < n) ? cnt[i] : 0;
    s[t] = v;
    __syncthreads();
    for (int off = 1; off < 256; off <<= 1) {
        int u = (t >= off) ? s[t - off] : 0;
        __syncthreads();
        s[t] += u;
        __syncthreads();
    }
    if (i < n) {
        int e = bbase[blockIdx.x] + s[t] - v;
        rowptr[i] = e;
        cursor[i] = e;
    }
}

__global__ __launch_bounds__(256) void fill2_kernel(const int* __restrict__ src,
                                                    const int* __restrict__ tgt,
                                                    const int* __restrict__ et,
                                                    int* __restrict__ cursor2,
                                                    int* __restrict__ csr_src2) {
    int e = blockIdx.x * 256 + threadIdx.x;
    if (e >= EE) return;
    int pos = atomicAdd(&cursor2[tgt[e] * RR + et[e]], 1);
    csr_src2[pos] = src[e];
}

// ================= generic MFMA GEMM (projection): C=A@Bt, A fp32 split, bias, bf16 mirror =================
#define BK 32
#define APAD 36

template <bool SPLITA, bool ACC, bool BIAS, bool RELU, bool BF16OUT>
__global__ __launch_bounds__(256) void gemm_mfma(const void* __restrict__ Av, int lda,
                                                 const unsigned short* __restrict__ Bthi,
                                                 const unsigned short* __restrict__ Btlo, int ldk,
                                                 float* __restrict__ C,
                                                 unsigned short* __restrict__ Cb,
                                                 const float* __restrict__ bias,
                                                 int M, int K) {
    __shared__ unsigned short Ah[128 * APAD];
    __shared__ unsigned short Al[(SPLITA ? 128 : 1) * APAD];
    __shared__ unsigned short Bh[128 * APAD];
    __shared__ unsigned short Bl[128 * APAD];
    const int tid  = threadIdx.x;
    const int m0   = blockIdx.x * 128;
    const int w    = tid >> 6;
    const int lane = tid & 63;
    const int lrow = lane & 15;
    const int q    = lane >> 4;

    f32x4 acc[2][8];
#pragma unroll
    for (int t = 0; t < 2; t++)
#pragma unroll
        for (int c = 0; c < 8; c++) acc[t][c] = (f32x4){0.f, 0.f, 0.f, 0.f};

    const int srow  = tid >> 1;
    const int spart = (tid & 1) * 16;

    for (int k0 = 0; k0 < K; k0 += BK) {
        if (SPLITA) {
            const float* A = (const float*)Av;
            int gm = m0 + srow;
            float va[16];
            if (gm < M) {
                const float* ap = &A[(size_t)gm * lda + k0 + spart];
#pragma unroll
                for (int j = 0; j < 4; j++) {
                    float4 v = *reinterpret_cast<const float4*>(ap + j * 4);
                    va[j * 4 + 0] = v.x; va[j * 4 + 1] = v.y; va[j * 4 + 2] = v.z; va[j * 4 + 3] = v.w;
                }
            } else {
#pragma unroll
                for (int j = 0; j < 16; j++) va[j] = 0.f;
            }
            unsigned hw[8], lw[8];
#pragma unroll
            for (int j = 0; j < 8; j++) {
                unsigned short h0 = f2bf(va[2 * j]);
                unsigned short h1 = f2bf(va[2 * j + 1]);
                unsigned short l0 = f2bf(va[2 * j] - bf2f(h0));
                unsigned short l1 = f2bf(va[2 * j + 1] - bf2f(h1));
                hw[j] = (unsigned)h0 | ((unsigned)h1 << 16);
                lw[j] = (unsigned)l0 | ((unsigned)l1 << 16);
            }
            *reinterpret_cast<uint4*>(&Ah[srow * APAD + spart])     = make_uint4(hw[0], hw[1], hw[2], hw[3]);
            *reinterpret_cast<uint4*>(&Ah[srow * APAD + spart + 8]) = make_uint4(hw[4], hw[5], hw[6], hw[7]);
            *reinterpret_cast<uint4*>(&Al[srow * APAD + spart])     = make_uint4(lw[0], lw[1], lw[2], lw[3]);
            *reinterpret_cast<uint4*>(&Al[srow * APAD + spart + 8]) = make_uint4(lw[4], lw[5], lw[6], lw[7]);
        } else {
            const unsigned short* A = (const unsigned short*)Av;
            int gm = m0 + srow;
            uint4 v  = make_uint4(0u, 0u, 0u, 0u);
            uint4 v2 = make_uint4(0u, 0u, 0u, 0u);
            if (gm < M) {
                const unsigned short* ap = &A[(size_t)gm * lda + k0 + spart];
                v  = *reinterpret_cast<const uint4*>(ap);
                v2 = *reinterpret_cast<const uint4*>(ap + 8);
            }
            *reinterpret_cast<uint4*>(&Ah[srow * APAD + spart])     = v;
            *reinterpret_cast<uint4*>(&Ah[srow * APAD + spart + 8]) = v2;
        }
        {
            const unsigned short* bh = &Bthi[(size_t)srow * ldk + k0 + spart];
            const unsigned short* bl = &Btlo[(size_t)srow * ldk + k0 + spart];
            *reinterpret_cast<uint4*>(&Bh[srow * APAD + spart])     = *reinterpret_cast<const uint4*>(bh);
            *reinterpret_cast<uint4*>(&Bh[srow * APAD + spart + 8]) = *reinterpret_cast<const uint4*>(bh + 8);
            *reinterpret_cast<uint4*>(&Bl[srow * APAD + spart])     = *reinterpret_cast<const uint4*>(bl);
            *reinterpret_cast<uint4*>(&Bl[srow * APAD + spart + 8]) = *reinterpret_cast<const uint4*>(bl + 8);
        }
        __syncthreads();

        short8 ah[2], al[2];
#pragma unroll
        for (int t = 0; t < 2; t++) {
            ah[t] = *reinterpret_cast<const short8*>(&Ah[(w * 32 + t * 16 + lrow) * APAD + q * 8]);
            if (SPLITA)
                al[t] = *reinterpret_cast<const short8*>(&Al[(w * 32 + t * 16 + lrow) * APAD + q * 8]);
        }
#pragma unroll
        for (int c = 0; c < 8; c++) {
            short8 bh = *reinterpret_cast<const short8*>(&Bh[(c * 16 + lrow) * APAD + q * 8]);
            short8 bl = *reinterpret_cast<const short8*>(&Bl[(c * 16 + lrow) * APAD + q * 8]);
#pragma unroll
            for (int t = 0; t < 2; t++) {
                acc[t][c] = __builtin_amdgcn_mfma_f32_16x16x32_bf16(ah[t], bl, acc[t][c], 0, 0, 0);
                if (SPLITA)
                    acc[t][c] = __builtin_amdgcn_mfma_f32_16x16x32_bf16(al[t], bh, acc[t][c], 0, 0, 0);
                acc[t][c] = __builtin_amdgcn_mfma_f32_16x16x32_bf16(ah[t], bh, acc[t][c], 0, 0, 0);
            }
        }
        __syncthreads();
    }

#pragma unroll
    for (int t = 0; t < 2; t++) {
#pragma unroll
        for (int r = 0; r < 4; r++) {
            int gm = m0 + w * 32 + t * 16 + q * 4 + r;
            if (gm >= M) continue;
#pragma unroll
            for (int c = 0; c < 8; c++) {
                int gn = c * 16 + lrow;
                float v = acc[t][c][r];
                if (BIAS) v += bias[gn];
                if (ACC)  v += C[(size_t)gm * HF + gn];
                if (RELU) v = fmaxf(v, 0.f);
                C[(size_t)gm * HF + gn] = v;
                if (BF16OUT) Cb[(size_t)gm * HF + gn] = f2bf(v);
            }
        }
    }
}

// ================= merged RGCN layer GEMM =================
// hout = relu( aggb[N,1024] @ W[0:1024]^T + hin[N,128] @ root^T + bias ), + bf16 mirror.
__global__ __launch_bounds__(256) void gemm_rgcn(const unsigned short* __restrict__ aggb,
                                                 const float* __restrict__ hin,
                                                 const unsigned short* __restrict__ Bthi,
                                                 const unsigned short* __restrict__ Btlo,
                                                 float* __restrict__ hout,
                                                 unsigned short* __restrict__ hbout,
                                                 const float* __restrict__ bias, int M) {
    const int LDK = (RR + 1) * HF;  // 1152
    __shared__ unsigned short Ah[128 * APAD];
    __shared__ unsigned short Al[128 * APAD];
    __shared__ unsigned short Bh[128 * APAD];
    __shared__ unsigned short Bl[128 * APAD];
    const int tid  = threadIdx.x;
    const int m0   = blockIdx.x * 128;
    const int w    = tid >> 6;
    const int lane = tid & 63;
    const int lrow = lane & 15;
    const int q    = lane >> 4;

    f32x4 acc[2][8];
#pragma unroll
    for (int t = 0; t < 2; t++)
#pragma unroll
        for (int c = 0; c < 8; c++) acc[t][c] = (f32x4){0.f, 0.f, 0.f, 0.f};

    const int srow  = tid >> 1;
    const int spart = (tid & 1) * 16;

    // ---- phase 1: K = 0..1024, A = aggb (bf16) ----
    for (int k0 = 0; k0 < RR * HF; k0 += BK) {
        {
            int gm = m0 + srow;
            uint4 v  = make_uint4(0u, 0u, 0u, 0u);
            uint4 v2 = make_uint4(0u, 0u, 0u, 0u);
            if (gm < M) {
                const unsigned short* ap = &aggb[(size_t)gm * (RR * HF) + k0 + spart];
                v  = *reinterpret_cast<const uint4*>(ap);
                v2 = *reinterpret_cast<const uint4*>(ap + 8);
            }
            *reinterpret_cast<uint4*>(&Ah[srow * APAD + spart])     = v;
            *reinterpret_cast<uint4*>(&Ah[srow * APAD + spart + 8]) = v2;
        }
        {
            const unsigned short* bh = &Bthi[(size_t)srow * LDK + k0 + spart];
            const unsigned short* bl = &Btlo[(size_t)srow * LDK + k0 + spart];
            *reinterpret_cast<uint4*>(&Bh[srow * APAD + spart])     = *reinterpret_cast<const uint4*>(bh);
            *reinterpret_cast<uint4*>(&Bh[srow * APAD + spart + 8]) = *reinterpret_cast<const uint4*>(bh + 8);
            *reinterpret_cast<uint4*>(&Bl[srow * APAD + spart])     = *reinterpret_cast<const uint4*>(bl);
            *reinterpret_cast<uint4*>(&Bl[srow * APAD + spart + 8]) = *reinterpret_cast<const uint4*>(bl + 8);
        }
        __syncthreads();
        short8 ah[2];
#pragma unroll
        for (int t = 0; t < 2; t++)
            ah[t] = *reinterpret_cast<const short8*>(&Ah[(w * 32 + t * 16 + lrow) * APAD + q * 8]);
#pragma unroll
        for (int c = 0; c < 8; c++) {
            short8 bh = *reinterpret_cast<const short8*>(&Bh[(c * 16 + lrow) * APAD + q * 8]);
            short8 bl = *reinterpret_cast<const short8*>(&Bl[(c * 16 + lrow) * APAD + q * 8]);
#pragma unroll
            for (int t = 0; t < 2; t++) {
                acc[t][c] = __builtin_amdgcn_mfma_f32_16x16x32_bf16(ah[t], bl, acc[t][c], 0, 0, 0);
                acc[t][c] = __builtin_amdgcn_mfma_f32_16x16x32_bf16(ah[t], bh, acc[t][c], 0, 0, 0);
            }
        }
        __syncthreads();
    }

    // ---- phase 2: K = 1024..1152, A = hin (fp32 split) ----
    for (int k0 = 0; k0 < HF; k0 += BK) {
        {
            int gm = m0 + srow;
            float va[16];
            if (gm < M) {
                const float* ap = &hin[(size_t)gm * HF + k0 + spart];
#pragma unroll
                for (int j = 0; j < 4; j++) {
                    float4 v = *reinterpret_cast<const float4*>(ap + j * 4);
                    va[j * 4 + 0] = v.x; va[j * 4 + 1] = v.y; va[j * 4 + 2] = v.z; va[j * 4 + 3] = v.w;
                }
            } else {
#pragma unroll
                for (int j = 0; j < 16; j++) va[j] = 0.f;
            }
            unsigned hw[8], lw[8];
#pragma unroll
            for (int j = 0; j < 8; j++) {
                unsigned short h0 = f2bf(va[2 * j]);
                unsigned short h1 = f2bf(va[2 * j + 1]);
                unsigned short l0 = f2bf(va[2 * j] - bf2f(h0));
                unsigned short l1 = f2bf(va[2 * j + 1] - bf2f(h1));
                hw[j] = (unsigned)h0 | ((unsigned)h1 << 16);
                lw[j] = (unsigned)l0 | ((unsigned)l1 << 16);
            }
            *reinterpret_cast<uint4*>(&Ah[srow * APAD + spart])     = make_uint4(hw[0], hw[1], hw[2], hw[3]);
            *reinterpret_cast<uint4*>(&Ah[srow * APAD + spart + 8]) = make_uint4(hw[4], hw[5], hw[6], hw[7]);
            *reinterpret_cast<uint4*>(&Al[srow * APAD + spart])     = make_uint4(lw[0], lw[1], lw[2], lw[3]);
            *reinterpret_cast<uint4*>(&Al[srow * APAD + spart + 8]) = make_uint4(lw[4], lw[5], lw[6], lw[7]);
        }
        {
            const unsigned short* bh = &Bthi[(size_t)srow * LDK + RR * HF + k0 + spart];
            const unsigned short* bl = &Btlo[(size_t)srow * LDK + RR * HF + k0 + spart];
            *reinterpret_cast<uint4*>(&Bh[srow * APAD + spart])     = *reinterpret_cast<const uint4*>(bh);
            *reinterpret_cast<uint4*>(&Bh[srow * APAD + spart + 8]) = *reinterpret_cast<const uint4*>(bh + 8);
            *reinterpret_cast<uint4*>(&Bl[srow * APAD + spart])     = *reinterpret_cast<const uint4*>(bl);
            *reinterpret_cast<uint4*>(&Bl[srow * APAD + spart + 8]) = *reinterpret_cast<const uint4*>(bl + 8);
        }
        __syncthreads();
        short8 ah[2], al[2];
#pragma unroll
        for (int t = 0; t < 2; t++) {
            ah[t] = *reinterpret_cast<const short8*>(&Ah[(w * 32 + t * 16 + lrow) * APAD + q * 8]);
            al[t] = *reinterpret_cast<const short8*>(&Al[(w * 32 + t * 16 + lrow) * APAD + q * 8]);
        }
#pragma unroll
        for (int c = 0; c < 8; c++) {
            short8 bh = *reinterpret_cast<const short8*>(&Bh[(c * 16 + lrow) * APAD + q * 8]);
            short8 bl = *reinterpret_cast<const short8*>(&Bl[(c * 16 + lrow) * APAD + q * 8]);
#pragma unroll
            for (int t = 0; t < 2; t++) {
                acc[t][c] = __builtin_amdgcn_mfma_f32_16x16x32_bf16(ah[t], bl, acc[t][c], 0, 0, 0);
                acc[t][c] = __builtin_amdgcn_mfma_f32_16x16x32_bf16(al[t], bh, acc[t][c], 0, 0, 0);
                acc[t][c] = __builtin_amdgcn_mfma_f32_16x16x32_bf16(ah[t], bh, acc[t][c], 0, 0, 0);
            }
        }
        __syncthreads();
    }

#pragma unroll
    for (int t = 0; t < 2; t++) {
#pragma unroll
        for (int r = 0; r < 4; r++) {
            int gm = m0 + w * 32 + t * 16 + q * 4 + r;
            if (gm >= M) continue;
#pragma unroll
            for (int c = 0; c < 8; c++) {
                int gn = c * 16 + lrow;
                float v = fmaxf(acc[t][c][r] + bias[gn], 0.f);
                hout[(size_t)gm * HF + gn] = v;
                hbout[(size_t)gm * HF + gn] = f2bf(v);
            }
        }
    }
}

// ================= z GEMM with fused attention scores =================
__global__ __launch_bounds__(256) void gemm_z(const float* __restrict__ hin,
                                              const unsigned short* __restrict__ Bthi,
                                              const unsigned short* __restrict__ Btlo,
                                              const float* __restrict__ att,
                                              unsigned short* __restrict__ zb,
                                              float* __restrict__ a_src,
                                              float* __restrict__ a_tgt, int M) {
    __shared__ unsigned short Ah[128 * APAD];
    __shared__ unsigned short Al[128 * APAD];
    __shared__ unsigned short Bh[128 * APAD];
    __shared__ unsigned short Bl[128 * APAD];
    const int tid  = threadIdx.x;
    const int m0   = blockIdx.x * 128;
    const int w    = tid >> 6;
    const int lane = tid & 63;
    const int lrow = lane & 15;
    const int q    = lane >> 4;

    f32x4 acc[2][8];
#pragma unroll
    for (int t = 0; t < 2; t++)
#pragma unroll
        for (int c = 0; c < 8; c++) acc[t][c] = (f32x4){0.f, 0.f, 0.f, 0.f};

    const int srow  = tid >> 1;
    const int spart = (tid & 1) * 16;

    for (int k0 = 0; k0 < HF; k0 += BK) {
        {
            int gm = m0 + srow;
            float va[16];
            if (gm < M) {
                const float* ap = &hin[(size_t)gm * HF + k0 + spart];
#pragma unroll
                for (int j = 0; j < 4; j++) {
                    float4 v = *reinterpret_cast<const float4*>(ap + j * 4);
                    va[j * 4 + 0] = v.x; va[j * 4 + 1] = v.y; va[j * 4 + 2] = v.z; va[j * 4 + 3] = v.w;
                }
            } else {
#pragma unroll
                for (int j = 0; j < 16; j++) va[j] = 0.f;
            }
            unsigned hw[8], lw[8];
#pragma unroll
            for (int j = 0; j < 8; j++) {
                unsigned short h0 = f2bf(va[2 * j]);
                unsigned short h1 = f2bf(va[2 * j + 1]);
                unsigned short l0 = f2bf(va[2 * j] - bf2f(h0));
                unsigned short l1 = f2bf(va[2 * j + 1] - bf2f(h1));
                hw[j] = (unsigned)h0 | ((unsigned)h1 << 16);
                lw[j] = (unsigned)l0 | ((unsigned)l1 << 16);
            }
            *reinterpret_cast<uint4*>(&Ah[srow * APAD + spart])     = make_uint4(hw[0], hw[1], hw[2], hw[3]);
            *reinterpret_cast<uint4*>(&Ah[srow * APAD + spart + 8]) = make_uint4(hw[4], hw[5], hw[6], hw[7]);
            *reinterpret_cast<uint4*>(&Al[srow * APAD + spart])     = make_uint4(lw[0], lw[1], lw[2], lw[3]);
            *reinterpret_cast<uint4*>(&Al[srow * APAD + spart + 8]) = make_uint4(lw[4], lw[5], lw[6], lw[7]);
        }
        {
            const unsigned short* bh = &Bthi[(size_t)srow * HF + k0 + spart];
            const unsigned short* bl = &Btlo[(size_t)srow * HF + k0 + spart];
            *reinterpret_cast<uint4*>(&Bh[srow * APAD + spart])     = *reinterpret_cast<const uint4*>(bh);
            *reinterpret_cast<uint4*>(&Bh[srow * APAD + spart + 8]) = *reinterpret_cast<const uint4*>(bh + 8);
            *reinterpret_cast<uint4*>(&Bl[srow * APAD + spart])     = *reinterpret_cast<const uint4*>(bl);
            *reinterpret_cast<uint4*>(&Bl[srow * APAD + spart + 8]) = *reinterpret_cast<const uint4*>(bl + 8);
        }
        __syncthreads();
        short8 ah[2], al[2];
#pragma unroll
        for (int t = 0; t < 2; t++) {
            ah[t] = *reinterpret_cast<const short8*>(&Ah[(w * 32 + t * 16 + lrow) * APAD + q * 8]);
            al[t] = *reinterpret_cast<const short8*>(&Al[(w * 32 + t * 16 + lrow) * APAD + q * 8]);
        }
#pragma unroll
        for (int c = 0; c < 8; c++) {
            short8 bh = *reinterpret_cast<const short8*>(&Bh[(c * 16 + lrow) * APAD + q * 8]);
            short8 bl = *reinterpret_cast<const short8*>(&Bl[(c * 16 + lrow) * APAD + q * 8]);
#pragma unroll
            for (int t = 0; t < 2; t++) {
                acc[t][c] = __builtin_amdgcn_mfma_f32_16x16x32_bf16(ah[t], bl, acc[t][c], 0, 0, 0);
                acc[t][c] = __builtin_amdgcn_mfma_f32_16x16x32_bf16(al[t], bh, acc[t][c], 0, 0, 0);
                acc[t][c] = __builtin_amdgcn_mfma_f32_16x16x32_bf16(ah[t], bh, acc[t][c], 0, 0, 0);
            }
        }
        __syncthreads();
    }

    float att_s[8], att_t[8];
#pragma unroll
    for (int c = 0; c < 8; c++) {
        att_s[c] = att[c * 32 + lrow];
        att_t[c] = att[c * 32 + 16 + lrow];
    }

#pragma unroll
    for (int t = 0; t < 2; t++) {
#pragma unroll
        for (int r = 0; r < 4; r++) {
            int gm = m0 + w * 32 + t * 16 + q * 4 + r;
            if (gm >= M) continue;
#pragma unroll
            for (int c = 0; c < 8; c++) {
                int gn = c * 16 + lrow;
                float v = acc[t][c][r];
                zb[(size_t)gm * HF + gn] = f2bf(v);
                float ps = v * att_s[c];
                float pt = v * att_t[c];
#pragma unroll
                for (int off = 1; off < 16; off <<= 1) {
                    ps += __shfl_xor(ps, off);
                    pt += __shfl_xor(pt, off);
                }
                if (lrow == 0) {
                    a_src[(size_t)gm * NHEADS + c] = ps;
                    a_tgt[(size_t)gm * NHEADS + c] = pt;
                }
            }
        }
    }
}

// ================= RGCN gather: (tgt,rel)-sorted segments, 2 edges/iter =================
__global__ __launch_bounds__(256) void rgcn_agg_sorted(const unsigned short* __restrict__ hb,
                                                       const int* __restrict__ rowptr2,
                                                       const int* __restrict__ csr_src2,
                                                       unsigned short* __restrict__ agg) {
    int w = (blockIdx.x * 256 + threadIdx.x) >> 6;
    if (w >= NN) return;
    int lane = threadIdx.x & 63;
    int half = lane >> 5;          // which edge of the pair
    int c4 = (lane & 31) * 4;      // 4 cols (8 B) of the 128-wide row
    const int b8 = w * RR;
    unsigned short* o = &agg[(size_t)w * (RR * HF)];
    int b = rowptr2[b8];
#pragma unroll
    for (int r = 0; r < RR; r++) {
        int e2 = rowptr2[b8 + r + 1];
        float a0 = 0.f, a1 = 0.f, a2 = 0.f, a3 = 0.f;
        for (int e = b + half; e < e2; e += 2) {
            int s = csr_src2[e];
            uint2 v = *reinterpret_cast<const uint2*>(&hb[(size_t)s * HF + c4]);
            a0 += bf2f((unsigned short)(v.x & 0xffffu));
            a1 += bf2f((unsigned short)(v.x >> 16));
            a2 += bf2f((unsigned short)(v.y & 0xffffu));
            a3 += bf2f((unsigned short)(v.y >> 16));
        }
        a0 += __shfl_xor(a0, 32);
        a1 += __shfl_xor(a1, 32);
        a2 += __shfl_xor(a2, 32);
        a3 += __shfl_xor(a3, 32);
        int n = e2 - b;
        float inv = 1.f / (float)(n > 1 ? n : 1);
        if (half == 0) {
            uint2 p;
            p.x = (unsigned)f2bf(a0 * inv) | ((unsigned)f2bf(a1 * inv) << 16);
            p.y = (unsigned)f2bf(a2 * inv) | ((unsigned)f2bf(a3 * inv) << 16);
            *reinterpret_cast<uint2*>(&o[r * HF + c4]) = p;
        }
        b = e2;
    }
}

// ================= GAT: two-pass (edge-parallel max, then FMA-only accumulate) =================
__global__ __launch_bounds__(256) void gat_kernel(const int* __restrict__ rowptr2,
                                                  const int* __restrict__ csr_src2,
                                                  const float* __restrict__ a_src,
                                                  const float* __restrict__ a_tgt,
                                                  const unsigned short* __restrict__ zb,
                                                  const float* __restrict__ bg,
                                                  const float* __restrict__ Wf,
                                                  const float* __restrict__ bf,
                                                  float* __restrict__ out) {
    int w = (blockIdx.x * 256 + threadIdx.x) >> 6;
    if (w >= NN) return;
    int lane = threadIdx.x & 63;
    int beg = rowptr2[w * RR], end = rowptr2[w * RR + RR];

    // ---- pass A: segment max, 8 edges x 8 heads in parallel ----
    int hdA = lane & 7;
    int e8  = lane >> 3;
    float atA = a_tgt[w * NHEADS + hdA];
    float m = -1e30f;
    for (int e = beg + e8; e < end; e += 8) {
        int s = csr_src2[e];
        float a = a_src[s * NHEADS + hdA] + atA;
        a = a > 0.f ? a : 0.2f * a;
        m = fmaxf(m, a);
    }
    m = fmaxf(m, __shfl_xor(m, 8));
    m = fmaxf(m, __shfl_xor(m, 16));
    m = fmaxf(m, __shfl_xor(m, 32));

    // ---- pass B: accumulate (no rescale chain), 2 independent chains ----
    int hd = lane >> 3;
    int c0 = lane * 2;
    float mB = __shfl(m, hd);      // lane 'hd' (hd<8) carries head hd's max
    float at = __shfl(atA, hd);
    float l0 = 0.f, l1 = 0.f;
    float ax0 = 0.f, ay0 = 0.f, ax1 = 0.f, ay1 = 0.f;
    int e = beg;
    for (; e + 1 < end; e += 2) {
        int s0 = csr_src2[e], s1 = csr_src2[e + 1];
        float a0 = a_src[s0 * NHEADS + hd] + at;
        float a1 = a_src[s1 * NHEADS + hd] + at;
        a0 = a0 > 0.f ? a0 : 0.2f * a0;
        a1 = a1 > 0.f ? a1 : 0.2f * a1;
        float w0 = __expf(a0 - mB);
        float w1 = __expf(a1 - mB);
        unsigned z0 = *reinterpret_cast<const unsigned*>(&zb[(size_t)s0 * HF + c0]);
        unsigned z1 = *reinterpret_cast<const unsigned*>(&zb[(size_t)s1 * HF + c0]);
        l0 += w0; l1 += w1;
        ax0 += bf2f((unsigned short)(z0 & 0xffffu)) * w0;
        ay0 += bf2f((unsigned short)(z0 >> 16)) * w0;
        ax1 += bf2f((unsigned short)(z1 & 0xffffu)) * w1;
        ay1 += bf2f((unsigned short)(z1 >> 16)) * w1;
    }
    if (e < end) {
        int s0 = csr_src2[e];
        float a0 = a_src[s0 * NHEADS + hd] + at;
        a0 = a0 > 0.f ? a0 : 0.2f * a0;
        float w0 = __expf(a0 - mB);
        unsigned z0 = *reinterpret_cast<const unsigned*>(&zb[(size_t)s0 * HF + c0]);
        l0 += w0;
        ax0 += bf2f((unsigned short)(z0 & 0xffffu)) * w0;
        ay0 += bf2f((unsigned short)(z0 >> 16)) * w0;
    }
    float l = l0 + l1;
    float ax = ax0 + ax1, ay = ay0 + ay1;

    float inv = 1.f / fmaxf(l, 1e-16f);
    float vx = ax * inv + bg[c0];
    float vy = ay * inv + bg[c0 + 1];

    float p0 = vx * Wf[c0 * 3 + 0] + vy * Wf[(c0 + 1) * 3 + 0];
    float p1 = vx * Wf[c0 * 3 + 1] + vy * Wf[(c0 + 1) * 3 + 1];
    float p2 = vx * Wf[c0 * 3 + 2] + vy * Wf[(c0 + 1) * 3 + 2];
#pragma unroll
    for (int off = 32; off > 0; off >>= 1) {
        p0 += __shfl_xor(p0, off);
        p1 += __shfl_xor(p1, off);
        p2 += __shfl_xor(p2, off);
    }
    if (lane == 0) {
        float l0v = p0 + bf[0], l1v = p1 + bf[1], l2v = p2 + bf[2];
        float mm = fmaxf(l0v, fmaxf(l1v, l2v));
        float lse = mm + logf(expf(l0v - mm) + expf(l1v - mm) + expf(l2v - mm));
        out[(size_t)w * 3 + 0] = l0v - lse;
        out[(size_t)w * 3 + 1] = l1v - lse;
        out[(size_t)w * 3 + 2] = l2v - lse;
    }
}

// ================= launch =================
extern "C" void kernel_launch(void* const* d_in, const int* in_sizes, int n_in,
                              void* d_out, int out_size, void* d_ws, size_t ws_size,
                              hipStream_t stream) {
    const float* x     = (const float*)d_in[0];
    const int*   ei    = (const int*)d_in[1];
    const int*   etype = (const int*)d_in[2];
    const float* Wp    = (const float*)d_in[3];
    const float* bp    = (const float*)d_in[4];
    const float* W1    = (const float*)d_in[5];
    const float* root1 = (const float*)d_in[6];
    const float* b1    = (const float*)d_in[7];
    const float* W2    = (const float*)d_in[8];
    const float* root2 = (const float*)d_in[9];
    const float* b2    = (const float*)d_in[10];
    const float* Wg    = (const float*)d_in[11];
    const float* att   = (const float*)d_in[12];
    const float* bg    = (const float*)d_in[13];
    const float* Wf    = (const float*)d_in[14];
    const float* bf    = (const float*)d_in[15];
    (void)in_sizes; (void)n_in; (void)out_size; (void)ws_size;

    const int* srcv = ei;
    const int* tgtv = ei + EE;

    // ---- workspace layout (bytes), ~185.4 MB ----
    char* base = (char*)d_ws;
    unsigned short* aggb = (unsigned short*)(base + 0);   // N*1024*2 = 102,400,000
    int* cnt2    = (int*)(base + 96000000);               // 1,600,000 (aliased, dead before walk 1)
    int* cursor2 = (int*)(base + 98000000);               // 1,600,000
    int* bsum2   = (int*)(base + 99700000);               // 6,256
    int* bbase2  = (int*)(base + 99800000);               // 6,256
    unsigned short* zb = (unsigned short*)(base + 0);     // 12,800,000 (GAT phase)
    float* a_src = (float*)(base + 12800000);             // 1,600,000
    float* a_tgt = (float*)(base + 14400000);             // 1,600,000
    float* h1    = (float*)(base + 102400000);            // 25,600,000
    float* h2    = (float*)(base + 128000000);            // 25,600,000
    unsigned short* h1b = (unsigned short*)(base + 153600000); // 12,800,000
    unsigned short* h2b = (unsigned short*)(base + 166400000); // 12,800,000
    int* csr_src2 = (int*)(base + 179200000);             // 3,200,000
    int* rowptr2  = (int*)(base + 182400000);             // 1,600,016
    unsigned short* Wtp_hi = (unsigned short*)(base + 184000016); // 65,536
    unsigned short* Wtp_lo = (unsigned short*)(base + 184065552); // 65,536
    unsigned short* Wt1_hi = (unsigned short*)(base + 184131088); // 294,912
    unsigned short* Wt1_lo = (unsigned short*)(base + 184426000); // 294,912
    unsigned short* Wt2_hi = (unsigned short*)(base + 184720912); // 294,912
    unsigned short* Wt2_lo = (unsigned short*)(base + 185015824); // 294,912
    unsigned short* Wtg_hi = (unsigned short*)(base + 185310736); // 32,768
    unsigned short* Wtg_lo = (unsigned short*)(base + 185343504); // 32,768

    // ---- weight prep: one dispatch ----
    prep_weights<<<cdiv(344064, 256), 256, 0, stream>>>(
        Wp, W1, root1, W2, root2, Wg,
        Wtp_hi, Wtp_lo, Wt1_hi, Wt1_lo, Wt2_hi, Wt2_lo, Wtg_hi, Wtg_lo);

    // ---- CSR build, sorted by (tgt, rel) ----
    hipMemsetAsync(cnt2, 0, (size_t)M2 * 4, stream);
    count2_kernel<<<cdiv(EE, 256), 256, 0, stream>>>(tgtv, etype, cnt2);
    scan1_kernel<<<NB2, 256, 0, stream>>>(cnt2, bsum2, M2);
    scan2_kernel<<<1, 256, 0, stream>>>(bsum2, bbase2, &rowptr2[M2], NB2, CH2);
    scan3_kernel<<<NB2, 256, 0, stream>>>(cnt2, bbase2, rowptr2, cursor2, M2);
    fill2_kernel<<<cdiv(EE, 256), 256, 0, stream>>>(srcv, tgtv, etype, cursor2, csr_src2);

    const int ggrid  = cdiv(NN, 128);   // 391
    const int nwgrid = cdiv(NN, 4);

    // ---- projection: h1 = x @ Wp + bp (fp32-effective) + h1b mirror ----
    gemm_mfma<true, false, true, false, true><<<ggrid, 256, 0, stream>>>(
        x, DIN, Wtp_hi, Wtp_lo, DIN, h1, h1b, bp, NN, DIN);

    // ---- RGCN layer 1: h1 -> h2 ----
    rgcn_agg_sorted<<<nwgrid, 256, 0, stream>>>(h1b, rowptr2, csr_src2, aggb);
    gemm_rgcn<<<ggrid, 256, 0, stream>>>(aggb, h1, Wt1_hi, Wt1_lo, h2, h2b, b1, NN);

    // ---- RGCN layer 2: h2 -> h1 ----
    rgcn_agg_sorted<<<nwgrid, 256, 0, stream>>>(h2b, rowptr2, csr_src2, aggb);
    gemm_rgcn<<<ggrid, 256, 0, stream>>>(aggb, h2, Wt2_hi, Wt2_lo, h1, h1b, b2, NN);

    // ---- GAT: z GEMM (fused scores) + two-pass softmax-aggregate ----
    gemm_z<<<ggrid, 256, 0, stream>>>(h1, Wtg_hi, Wtg_lo, att, zb, a_src, a_tgt, NN);
    gat_kernel<<<nwgrid, 256, 0, stream>>>(rowptr2, csr_src2, a_src, a_tgt, zb, bg, Wf, bf, (float*)d_out);
}